// Round 7
// baseline (8408.333 us; speedup 1.0000x reference)
//
#include <hip/hip_runtime.h>
#include <math.h>

#define H 128
#define NN 100000
#define E_AST 100000
#define E_MST 20000
#define E_TOT 240000
#define NV 30000
#define NP 8000
#define N4 400000
#define NH 12800000   // NN * H

typedef unsigned short ushort_t;
typedef __attribute__((ext_vector_type(8))) unsigned short us8;
typedef _Float16 half8 __attribute__((ext_vector_type(8)));
typedef __attribute__((ext_vector_type(4))) float f32x4;

__device__ __forceinline__ unsigned short f2h(float f) {
    _Float16 h = (_Float16)f;
    return __builtin_bit_cast(unsigned short, h);
}
__device__ __forceinline__ void fsplit(float x, unsigned short& hi, unsigned short& lo) {
    _Float16 a = (_Float16)x;
    _Float16 b = (_Float16)(x - (float)a);
    hi = __builtin_bit_cast(unsigned short, a);
    lo = __builtin_bit_cast(unsigned short, b);
}

#define GLD16(gsrc, ldst) __builtin_amdgcn_global_load_lds( \
    (const __attribute__((address_space(1))) unsigned int*)(gsrc), \
    (__attribute__((address_space(3))) unsigned int*)(ldst), 16, 0, 0)

// ---------------- embedding -> h fp32 ----------------
__global__ void embed_kernel(const int* __restrict__ ids, const float* __restrict__ emb,
                             float* __restrict__ h) {
    int g = blockIdx.x * 256 + threadIdx.x;
    if (g >= NN * 64) return;
    int i = g >> 6, j2 = (g & 63) << 1;
    *(float2*)&h[(size_t)i * H + j2] = *(const float2*)&emb[(size_t)ids[i] * H + j2];
}

// ---------------- CSR build over keys (tgt*4 + e), payload src ----------------
__device__ inline void edge_decode(int t, const int* __restrict__ ast, const int* __restrict__ mst,
                                   int& e, int& src, int& tgt) {
    if (t < E_AST)                 { e = 0; src = ast[2*t];     tgt = ast[2*t+1]; }
    else if (t < 2*E_AST)          { int i = t - E_AST;         e = 1; src = ast[2*i+1]; tgt = ast[2*i]; }
    else if (t < 2*E_AST + E_MST)  { int i = t - 2*E_AST;       e = 2; src = mst[2*i];   tgt = mst[2*i+1]; }
    else                           { int i = t - 2*E_AST-E_MST; e = 3; src = mst[2*i+1]; tgt = mst[2*i]; }
}

__global__ void count4_kernel(const int* __restrict__ ast, const int* __restrict__ mst,
                              int* __restrict__ deg4) {
    int t = blockIdx.x * 256 + threadIdx.x;
    if (t >= E_TOT) return;
    int e, src, tgt; edge_decode(t, ast, mst, e, src, tgt);
    atomicAdd(&deg4[tgt * 4 + e], 1);
}

__global__ void scan1b(const int* __restrict__ deg, int* __restrict__ excl,
                       int* __restrict__ partial, int n) {
    __shared__ int sm[256];
    int t = threadIdx.x, b = blockIdx.x;
    int base = b * 2048 + t * 8;
    int v[8]; int s = 0;
    #pragma unroll
    for (int i = 0; i < 8; ++i) { v[i] = (base + i < n) ? deg[base + i] : 0; s += v[i]; }
    sm[t] = s;
    __syncthreads();
    for (int off = 1; off < 256; off <<= 1) {
        int x = (t >= off) ? sm[t - off] : 0;
        __syncthreads();
        sm[t] += x;
        __syncthreads();
    }
    int run = sm[t] - s;
    if (t == 255) partial[b] = sm[255];
    #pragma unroll
    for (int i = 0; i < 8; ++i) {
        if (base + i < n) { excl[base + i] = run; run += v[i]; }
    }
}

__global__ void scan2(int* __restrict__ partial, int nb) {
    __shared__ int sm[256];
    int t = threadIdx.x;
    int v = (t < nb) ? partial[t] : 0;
    sm[t] = v;
    __syncthreads();
    for (int off = 1; off < 256; off <<= 1) {
        int x = (t >= off) ? sm[t - off] : 0;
        __syncthreads();
        sm[t] += x;
        __syncthreads();
    }
    if (t < nb) partial[t] = sm[t] - v;
}

__global__ void scan3b(int* __restrict__ rp, const int* __restrict__ partial, int n, int etot) {
    int i = blockIdx.x * 256 + threadIdx.x;
    if (i < n) rp[i] += partial[i >> 11];
    if (i == n) rp[n] = etot;
}

__global__ void fill4_kernel(const int* __restrict__ ast, const int* __restrict__ mst,
                             const int* __restrict__ rp4, int* __restrict__ cnt4,
                             int* __restrict__ col) {
    int t = blockIdx.x * 256 + threadIdx.x;
    if (t >= E_TOT) return;
    int e, src, tgt; edge_decode(t, ast, mst, e, src, tgt);
    int key = tgt * 4 + e;
    int slot = rp4[key] + atomicAdd(&cnt4[key], 1);
    col[slot] = src;
}

// ---------------- weight prep ----------------
__global__ void prep_wmsg2(const float* __restrict__ W, ushort_t* __restrict__ hi,
                           ushort_t* __restrict__ lo) {
    int i = blockIdx.x * 256 + threadIdx.x;
    if (i >= 262144) return;
    fsplit(W[i], hi[i], lo[i]);
}

// merged gate matrix Bg: rows 4j+{0:r,1:z,2:inn,3:hn} over K=[Wih-cols | Whh-cols]
// inn rows: zeros over Whh-part; hn rows: zeros over Wih-part.
__global__ void prep_Bg(const float* __restrict__ Wih_a, const float* __restrict__ Wih_b,
                        const float* __restrict__ Whh,
                        ushort_t* __restrict__ Bh, ushort_t* __restrict__ Bl) {
    int i = blockIdx.x * 256 + threadIdx.x;
    if (i >= 655360) return;
    int l, off, K;
    if (i < 131072)      { l = 0; off = 0;      K = 256; }
    else if (i < 327680) { l = 1; off = 131072; K = 384; }
    else if (i < 458752) { l = 2; off = 327680; K = 256; }
    else                 { l = 3; off = 458752; K = 384; }
    int Kx = K - 128;
    const float* Wih = (l & 1) ? (Wih_b + (size_t)(l >> 1) * 384 * 256)
                               : (Wih_a + (size_t)(l >> 1) * 384 * 128);
    const float* WhhL = Whh + (size_t)l * 384 * 128;
    int rem = i - off;
    int row = rem / K, k = rem - row * K;
    int j = row >> 2, s = row & 3;
    float v;
    if (s == 0)      v = (k < Kx) ? Wih[(size_t)j * Kx + k]         : WhhL[(size_t)j * 128 + (k - Kx)];
    else if (s == 1) v = (k < Kx) ? Wih[(size_t)(128 + j) * Kx + k] : WhhL[(size_t)(128 + j) * 128 + (k - Kx)];
    else if (s == 2) v = (k < Kx) ? Wih[(size_t)(256 + j) * Kx + k] : 0.f;
    else             v = (k < Kx) ? 0.f : WhhL[(size_t)(256 + j) * 128 + (k - Kx)];
    fsplit(v, Bh[i], Bl[i]);
}

// ---------------- msg GEMM: T[NN][128] = h @ W_e^T (split fp16, 3 products) ----------------
__global__ __launch_bounds__(256) void msg_gemm(
    const float* __restrict__ h, const ushort_t* __restrict__ Whi,
    const ushort_t* __restrict__ Wlo, float* __restrict__ T)
{
    __shared__ ushort_t Ahi[128 * 64], Alo[128 * 64], Bs[128 * 64];
    const int tid = threadIdx.x, w = tid >> 6, l = tid & 63;
    const int m0 = blockIdx.x * 128;
    const int wm = w >> 1, wn = w & 1;
    f32x4 acc[4][4];
    #pragma unroll
    for (int a = 0; a < 4; ++a)
        #pragma unroll
        for (int b = 0; b < 4; ++b) acc[a][b] = (f32x4){0.f, 0.f, 0.f, 0.f};

    for (int kt = 0; kt < 2; ++kt) {
        const int kk = kt * 64;
        {
            int r = tid >> 1, half = tid & 1;
            int grow = m0 + r; if (grow >= NN) grow = NN - 1;
            const float* s = h + (size_t)grow * H + kk + half * 32;
            ushort_t hi32[32], lo32[32];
            #pragma unroll
            for (int q = 0; q < 8; ++q) {
                float4 v = *(const float4*)&s[q * 4];
                fsplit(v.x, hi32[q*4+0], lo32[q*4+0]);
                fsplit(v.y, hi32[q*4+1], lo32[q*4+1]);
                fsplit(v.z, hi32[q*4+2], lo32[q*4+2]);
                fsplit(v.w, hi32[q*4+3], lo32[q*4+3]);
            }
            #pragma unroll
            for (int gq = 0; gq < 4; ++gq) {
                int g = half * 4 + gq;
                int slot = g ^ (r & 7);
                *(us8*)&Ahi[r * 64 + slot * 8] = *(us8*)&hi32[gq * 8];
                *(us8*)&Alo[r * 64 + slot * 8] = *(us8*)&lo32[gq * 8];
            }
        }
        #pragma unroll
        for (int q = 0; q < 4; ++q) {
            int row8 = w * 4 + q;
            const ushort_t* gs = Whi + (size_t)(row8 * 8 + (l >> 3)) * 128 + kk + ((l & 7) ^ (l >> 3)) * 8;
            GLD16(gs, &Bs[row8 * 512]);
        }
        __syncthreads();
        #pragma unroll
        for (int fk = 0; fk < 2; ++fk) {
            half8 ah[4], al[4], bh[4];
            #pragma unroll
            for (int fm = 0; fm < 4; ++fm) {
                int row = wm * 64 + fm * 16 + (l & 15);
                int slot = (fk * 4 + (l >> 4)) ^ (row & 7);
                ah[fm] = *(const half8*)&Ahi[row * 64 + slot * 8];
                al[fm] = *(const half8*)&Alo[row * 64 + slot * 8];
            }
            #pragma unroll
            for (int fn = 0; fn < 4; ++fn) {
                int row = wn * 64 + fn * 16 + (l & 15);
                int slot = (fk * 4 + (l >> 4)) ^ (row & 7);
                bh[fn] = *(const half8*)&Bs[row * 64 + slot * 8];
            }
            #pragma unroll
            for (int fm = 0; fm < 4; ++fm)
                #pragma unroll
                for (int fn = 0; fn < 4; ++fn) {
                    acc[fm][fn] = __builtin_amdgcn_mfma_f32_16x16x32_f16(ah[fm], bh[fn], acc[fm][fn], 0, 0, 0);
                    acc[fm][fn] = __builtin_amdgcn_mfma_f32_16x16x32_f16(al[fm], bh[fn], acc[fm][fn], 0, 0, 0);
                }
        }
        __syncthreads();
        #pragma unroll
        for (int q = 0; q < 4; ++q) {
            int row8 = w * 4 + q;
            const ushort_t* gs = Wlo + (size_t)(row8 * 8 + (l >> 3)) * 128 + kk + ((l & 7) ^ (l >> 3)) * 8;
            GLD16(gs, &Bs[row8 * 512]);
        }
        __syncthreads();
        #pragma unroll
        for (int fk = 0; fk < 2; ++fk) {
            half8 ah[4], bl[4];
            #pragma unroll
            for (int fm = 0; fm < 4; ++fm) {
                int row = wm * 64 + fm * 16 + (l & 15);
                int slot = (fk * 4 + (l >> 4)) ^ (row & 7);
                ah[fm] = *(const half8*)&Ahi[row * 64 + slot * 8];
            }
            #pragma unroll
            for (int fn = 0; fn < 4; ++fn) {
                int row = wn * 64 + fn * 16 + (l & 15);
                int slot = (fk * 4 + (l >> 4)) ^ (row & 7);
                bl[fn] = *(const half8*)&Bs[row * 64 + slot * 8];
            }
            #pragma unroll
            for (int fm = 0; fm < 4; ++fm)
                #pragma unroll
                for (int fn = 0; fn < 4; ++fn)
                    acc[fm][fn] = __builtin_amdgcn_mfma_f32_16x16x32_f16(ah[fm], bl[fn], acc[fm][fn], 0, 0, 0);
        }
        __syncthreads();
    }
    #pragma unroll
    for (int fm = 0; fm < 4; ++fm)
        #pragma unroll
        for (int fn = 0; fn < 4; ++fn) {
            int cc = wn * 64 + fn * 16 + (l & 15);
            #pragma unroll
            for (int rg = 0; rg < 4; ++rg) {
                int row = m0 + wm * 64 + fm * 16 + (l >> 4) * 4 + rg;
                if (row < NN) T[(size_t)row * H + cc] = acc[fm][fn][rg];
            }
        }
}

// ---------------- gather over CSR quarter e ----------------
__global__ void gather_q(const float* __restrict__ T, const int* __restrict__ rp4,
                         const int* __restrict__ col, const int* __restrict__ deg4,
                         const float* __restrict__ mb, float* __restrict__ inc, int e) {
    int wv = threadIdx.x >> 6, l = threadIdx.x & 63;
    int t = blockIdx.x * 4 + wv;
    if (t >= NN) return;
    int c2 = l * 2;
    float2 a;
    if (e == 0) {
        a = make_float2(0.f, 0.f);
        #pragma unroll
        for (int e4 = 0; e4 < 4; ++e4) {
            float d = (float)deg4[t * 4 + e4];
            a.x += d * mb[e4 * H + c2];
            a.y += d * mb[e4 * H + c2 + 1];
        }
    } else {
        a = *(const float2*)&inc[(size_t)t * H + c2];
    }
    int s0 = rp4[4 * t + e], s1 = rp4[4 * t + e + 1];
    for (int s = s0; s < s1; ++s) {
        float2 v = *(const float2*)&T[(size_t)col[s] * H + c2];
        a.x += v.x; a.y += v.y;
    }
    *(float2*)&inc[(size_t)t * H + c2] = a;
}

// ---------------- fused GRU GEMM: all 4 gates (N=512 interleaved 4j+s) + epilogue ----------------
// CFG 0: [inc,h] K=256; 1: [inc,emb,h] K=384; 2: [inc,s1h,h] K=384
template<int CFG>
__global__ __launch_bounds__(256) void gru_gemm(
    const float* __restrict__ inc, float* __restrict__ h,
    const ushort_t* __restrict__ s1h, const float* __restrict__ emb, const int* __restrict__ ids,
    const ushort_t* __restrict__ Bhi, const ushort_t* __restrict__ Blo,
    const float* __restrict__ bihL, const float* __restrict__ bhhL)
{
    constexpr int NPARTS = (CFG == 0) ? 2 : 3;
    constexpr int K = NPARTS * 128;
    constexpr int NCH = NPARTS * 2;
    __shared__ ushort_t Ahi[64 * 64];
    __shared__ ushort_t Alo[64 * 64];
    __shared__ ushort_t Bs[512 * 64];
    const int tid = threadIdx.x, w = tid >> 6, l = tid & 63;
    const int m0 = blockIdx.x * 64;

    f32x4 acc[4][8];
    #pragma unroll
    for (int a = 0; a < 4; ++a)
        #pragma unroll
        for (int b = 0; b < 8; ++b) acc[a][b] = (f32x4){0.f, 0.f, 0.f, 0.f};

    // A reg-staging geometry: 4 lanes per row, 16 floats each
    const int ar = tid >> 2, ac4 = tid & 3;
    int agrow = m0 + ar; if (agrow >= NN) agrow = NN - 1;
    float aR[16];

    // chunk meta (compile-time within unrolled loop):
    //   p = c>>1, kk = (c&1)*64; fp32-type unless (CFG==2 && p==1)
    //   next-fp32 chunk: CFG2: 1 -> 4 (skip s1 chunks); else c+1
    #define ISSUE_A(cn) { \
        int p_ = (cn) >> 1, kk_ = ((cn) & 1) * 64; \
        const float* s_; \
        if (p_ == 0) s_ = inc + (size_t)agrow * H; \
        else if (p_ == NPARTS - 1) s_ = h + (size_t)agrow * H; \
        else s_ = emb + (size_t)ids[agrow] * H; \
        s_ += kk_ + ac4 * 16; \
        _Pragma("unroll") \
        for (int q_ = 0; q_ < 4; ++q_) { \
            float4 v_ = *(const float4*)&s_[q_ * 4]; \
            aR[q_*4+0] = v_.x; aR[q_*4+1] = v_.y; aR[q_*4+2] = v_.z; aR[q_*4+3] = v_.w; \
        } }

    ISSUE_A(0);

    #pragma unroll
    for (int c = 0; c < NCH; ++c) {
        const int p = c >> 1;
        const int kk = (c & 1) * 64;
        const int kb = p * 128 + kk;
        const bool isS1 = (CFG == 2) && (p == 1);
        const bool useAlo = (p == 0);

        // ---- stage A ----
        if (isS1) {
            #pragma unroll
            for (int q = 0; q < 2; ++q) {
                int row8 = w * 2 + q;
                int row = row8 * 8 + (l >> 3);
                int grow = m0 + row; if (grow >= NN) grow = NN - 1;
                const ushort_t* gs = s1h + (size_t)grow * H + kk + ((l & 7) ^ (l >> 3)) * 8;
                GLD16(gs, &Ahi[row8 * 512]);
            }
        } else {
            ushort_t hi16[16], lo16[16];
            #pragma unroll
            for (int q = 0; q < 16; ++q) fsplit(aR[q], hi16[q], lo16[q]);
            #pragma unroll
            for (int gq = 0; gq < 2; ++gq) {
                int slot = (ac4 * 2 + gq) ^ (ar & 7);
                *(us8*)&Ahi[ar * 64 + slot * 8] = *(us8*)&hi16[gq * 8];
                if (useAlo) *(us8*)&Alo[ar * 64 + slot * 8] = *(us8*)&lo16[gq * 8];
            }
            // prefetch next fp32 chunk's A into regs (in flight across MFMA phases)
            int nf = (CFG == 2) ? ((c == 0) ? 1 : (c == 1) ? 4 : (c == 4) ? 5 : -1)
                                : ((c < NCH - 1) ? c + 1 : -1);
            if (nf >= 0) { ISSUE_A(nf); }
        }
        // ---- stage B hi ----
        #pragma unroll
        for (int q = 0; q < 16; ++q) {
            int row8 = w * 16 + q;
            const ushort_t* gs = Bhi + (size_t)(row8 * 8 + (l >> 3)) * K + kb + ((l & 7) ^ (l >> 3)) * 8;
            GLD16(gs, &Bs[row8 * 512]);
        }
        __syncthreads();
        // ---- MFMA hi phase ----
        #pragma unroll
        for (int fk = 0; fk < 2; ++fk) {
            half8 av[4], alv[4], bv[8];
            #pragma unroll
            for (int fm = 0; fm < 4; ++fm) {
                int row = fm * 16 + (l & 15);
                int slot = (fk * 4 + (l >> 4)) ^ (row & 7);
                av[fm] = *(const half8*)&Ahi[row * 64 + slot * 8];
                if (useAlo) alv[fm] = *(const half8*)&Alo[row * 64 + slot * 8];
            }
            #pragma unroll
            for (int fn = 0; fn < 8; ++fn) {
                int row = w * 128 + fn * 16 + (l & 15);
                int slot = (fk * 4 + (l >> 4)) ^ (row & 7);
                bv[fn] = *(const half8*)&Bs[row * 64 + slot * 8];
            }
            #pragma unroll
            for (int fm = 0; fm < 4; ++fm)
                #pragma unroll
                for (int fn = 0; fn < 8; ++fn) {
                    acc[fm][fn] = __builtin_amdgcn_mfma_f32_16x16x32_f16(av[fm], bv[fn], acc[fm][fn], 0, 0, 0);
                    if (useAlo)
                        acc[fm][fn] = __builtin_amdgcn_mfma_f32_16x16x32_f16(alv[fm], bv[fn], acc[fm][fn], 0, 0, 0);
                }
        }
        __syncthreads();
        // ---- stage B lo ----
        #pragma unroll
        for (int q = 0; q < 16; ++q) {
            int row8 = w * 16 + q;
            const ushort_t* gs = Blo + (size_t)(row8 * 8 + (l >> 3)) * K + kb + ((l & 7) ^ (l >> 3)) * 8;
            GLD16(gs, &Bs[row8 * 512]);
        }
        __syncthreads();
        // ---- MFMA lo phase ----
        #pragma unroll
        for (int fk = 0; fk < 2; ++fk) {
            half8 av[4], bv[8];
            #pragma unroll
            for (int fm = 0; fm < 4; ++fm) {
                int row = fm * 16 + (l & 15);
                int slot = (fk * 4 + (l >> 4)) ^ (row & 7);
                av[fm] = *(const half8*)&Ahi[row * 64 + slot * 8];
            }
            #pragma unroll
            for (int fn = 0; fn < 8; ++fn) {
                int row = w * 128 + fn * 16 + (l & 15);
                int slot = (fk * 4 + (l >> 4)) ^ (row & 7);
                bv[fn] = *(const half8*)&Bs[row * 64 + slot * 8];
            }
            #pragma unroll
            for (int fm = 0; fm < 4; ++fm)
                #pragma unroll
                for (int fn = 0; fn < 8; ++fn)
                    acc[fm][fn] = __builtin_amdgcn_mfma_f32_16x16x32_f16(av[fm], bv[fn], acc[fm][fn], 0, 0, 0);
        }
        __syncthreads();
    }
    #undef ISSUE_A

    // ---- GRU epilogue: quad (r,z,inn,hn) at cols 4j+s via intra-quad shfl ----
    #pragma unroll
    for (int fn = 0; fn < 8; ++fn) {
        int cc = w * 128 + fn * 16 + (l & 15);
        int j = cc >> 2, s = cc & 3;
        float bsum = (s == 0) ? bihL[j] + bhhL[j]
                   : (s == 1) ? bihL[128 + j] + bhhL[128 + j]
                   : (s == 2) ? bihL[256 + j] : bhhL[256 + j];
        #pragma unroll
        for (int fm = 0; fm < 4; ++fm) {
            #pragma unroll
            for (int rg = 0; rg < 4; ++rg) {
                int row = m0 + fm * 16 + (l >> 4) * 4 + rg;
                float pre = acc[fm][fn][rg] + bsum;
                float g = (s < 2) ? 1.f / (1.f + __expf(-pre)) : pre;
                float o1 = __shfl_xor(g, 1);
                float o2 = __shfl_xor(g, 2);
                float o3 = __shfl_xor(o1, 2);
                if (s == 0 && row < NN) {
                    float r = g, z = o1, inn = o2, hn = o3;
                    float n = tanhf(inn + r * hn);
                    float hold = h[(size_t)row * H + j];
                    h[(size_t)row * H + j] = (1.f - z) * n + z * hold;
                }
            }
        }
    }
}

// ---------------- s1 snapshot: h fp32 -> fp16 ----------------
__global__ void h2h16(const float* __restrict__ h, ushort_t* __restrict__ s1h) {
    int g = blockIdx.x * 256 + threadIdx.x;
    if (g >= NN * 64) return;
    float2 v = *(const float2*)&h[(size_t)g * 2];
    unsigned pk = (unsigned)f2h(v.x) | ((unsigned)f2h(v.y) << 16);
    *(unsigned*)&s1h[(size_t)g * 2] = pk;
}

// ---------------- output gathers ----------------
__global__ void out_gather(const float* __restrict__ h, const int* __restrict__ idx,
                           float* __restrict__ out, int n) {
    int g = blockIdx.x * 256 + threadIdx.x;
    if (g >= n * 64) return;
    int v = g >> 6, j2 = (g & 63) << 1;
    *(float2*)&out[(size_t)v * H + j2] = *(const float2*)&h[(size_t)idx[v] * H + j2];
}

extern "C" void kernel_launch(void* const* d_in, const int* in_sizes, int n_in,
                              void* d_out, int out_size, void* d_ws, size_t ws_size,
                              hipStream_t stream) {
    const int*   ids    = (const int*)d_in[0];
    const int*   ast    = (const int*)d_in[1];
    const int*   mst    = (const int*)d_in[2];
    const int*   varpos = (const int*)d_in[3];
    const int*   predid = (const int*)d_in[4];
    const float* emb    = (const float*)d_in[5];
    const float* msg_W  = (const float*)d_in[6];
    const float* msg_b  = (const float*)d_in[7];
    const float* Wih_a  = (const float*)d_in[8];
    const float* Wih_b  = (const float*)d_in[9];
    const float* Whh    = (const float*)d_in[10];
    const float* bih    = (const float*)d_in[11];
    const float* bhh    = (const float*)d_in[12];

    float* out = (float*)d_out;
    float* h   = out;                              // h fp32 lives in d_out

    int* ibase = (int*)(out + NH);
    int* deg4  = ibase;                            // 400000
    int* rp4   = ibase + 400000;                   // 400001
    int* cnt4  = ibase + 800001;                   // 400000
    int* col   = ibase + 1200001;                  // 240000
    int* part  = ibase + 1440001;                  // 256
    ushort_t* WT  = (ushort_t*)(ibase + 1500000);
    ushort_t* wmh = WT;                            // 262144
    ushort_t* wml = WT + 262144;                   // 262144
    ushort_t* Bgh = WT + 524288;                   // 655360
    ushort_t* Bgl = WT + 1179648;                  // 655360 (end 1835008)

    if (ws_size < (size_t)153600000) return;
    char* wsb = (char*)d_ws;
    float*    inc = (float*)wsb;                   // 51.2 MB [NN][128]
    ushort_t* s1h = (ushort_t*)(wsb + 51200000);   // 25.6 MB
    float*    T   = (float*)(wsb + 76800000);      // 51.2 MB

    embed_kernel<<<25000, 256, 0, stream>>>(ids, emb, h);

    hipMemsetAsync(deg4, 0, N4 * sizeof(int), stream);
    hipMemsetAsync(cnt4, 0, N4 * sizeof(int), stream);
    count4_kernel<<<(E_TOT + 255) / 256, 256, 0, stream>>>(ast, mst, deg4);
    scan1b<<<196, 256, 0, stream>>>(deg4, rp4, part, N4);
    scan2<<<1, 256, 0, stream>>>(part, 196);
    scan3b<<<1563, 256, 0, stream>>>(rp4, part, N4, E_TOT);
    fill4_kernel<<<(E_TOT + 255) / 256, 256, 0, stream>>>(ast, mst, rp4, cnt4, col);
    prep_wmsg2<<<1024, 256, 0, stream>>>(msg_W, wmh, wml);
    prep_Bg<<<2560, 256, 0, stream>>>(Wih_a, Wih_b, Whh, Bgh, Bgl);

    const int LT[4] = {5, 2, 5, 2};
    const size_t Eoff[4] = {0, 131072, 327680, 458752};
    for (int layer = 0; layer < 4; ++layer) {
        const float* bihL = bih + layer * 384;
        const float* bhhL = bhh + layer * 384;
        const float* mbL  = msg_b + (size_t)layer * 512;
        const ushort_t* BhL = Bgh + Eoff[layer];
        const ushort_t* BlL = Bgl + Eoff[layer];

        for (int ts = 0; ts < LT[layer]; ++ts) {
            for (int e = 0; e < 4; ++e) {
                const ushort_t* WhiE = wmh + ((size_t)layer * 4 + e) * 16384;
                const ushort_t* WloE = wml + ((size_t)layer * 4 + e) * 16384;
                msg_gemm<<<782, 256, 0, stream>>>(h, WhiE, WloE, T);
                gather_q<<<25000, 256, 0, stream>>>(T, rp4, col, deg4, mbL, inc, e);
            }
            if (layer == 0 || layer == 2)
                gru_gemm<0><<<1563, 256, 0, stream>>>(inc, h, s1h, emb, ids, BhL, BlL, bihL, bhhL);
            else if (layer == 1)
                gru_gemm<1><<<1563, 256, 0, stream>>>(inc, h, s1h, emb, ids, BhL, BlL, bihL, bhhL);
            else
                gru_gemm<2><<<1563, 256, 0, stream>>>(inc, h, s1h, emb, ids, BhL, BlL, bihL, bhhL);
        }
        if (layer == 0)
            h2h16<<<25000, 256, 0, stream>>>(h, s1h);
    }

    out_gather<<<(NV * 64 + 255) / 256, 256, 0, stream>>>(h, varpos, out + NH, NV);
    out_gather<<<(NP * 64 + 255) / 256, 256, 0, stream>>>(h, predid, out + NH + (size_t)NV * H, NP);
}

// Round 8
// 6925.658 us; speedup vs baseline: 1.2141x; 1.2141x over previous
//
#include <hip/hip_runtime.h>
#include <math.h>

#define H 128
#define NN 100000
#define E_AST 100000
#define E_MST 20000
#define E_TOT 240000
#define NV 30000
#define NP 8000
#define N4 400000
#define NH 12800000   // NN * H

typedef unsigned short ushort_t;
typedef __attribute__((ext_vector_type(8))) unsigned short us8;
typedef _Float16 half8 __attribute__((ext_vector_type(8)));
typedef __attribute__((ext_vector_type(4))) float f32x4;

__device__ __forceinline__ unsigned short f2h(float f) {
    _Float16 h = (_Float16)f;
    return __builtin_bit_cast(unsigned short, h);
}
__device__ __forceinline__ float h2f(unsigned short u) {
    return (float)__builtin_bit_cast(_Float16, u);
}
__device__ __forceinline__ void fsplit(float x, unsigned short& hi, unsigned short& lo) {
    _Float16 a = (_Float16)x;
    _Float16 b = (_Float16)(x - (float)a);
    hi = __builtin_bit_cast(unsigned short, a);
    lo = __builtin_bit_cast(unsigned short, b);
}

#define GLD16(gsrc, ldst) __builtin_amdgcn_global_load_lds( \
    (const __attribute__((address_space(1))) unsigned int*)(gsrc), \
    (__attribute__((address_space(3))) unsigned int*)(ldst), 16, 0, 0)

// ---------------- embedding -> h fp32 ----------------
__global__ void embed_kernel(const int* __restrict__ ids, const float* __restrict__ emb,
                             float* __restrict__ h) {
    int g = blockIdx.x * 256 + threadIdx.x;
    if (g >= NN * 64) return;
    int i = g >> 6, j2 = (g & 63) << 1;
    *(float2*)&h[(size_t)i * H + j2] = *(const float2*)&emb[(size_t)ids[i] * H + j2];
}

// ---------------- CSR build over keys (tgt*4 + e), payload src ----------------
__device__ inline void edge_decode(int t, const int* __restrict__ ast, const int* __restrict__ mst,
                                   int& e, int& src, int& tgt) {
    if (t < E_AST)                 { e = 0; src = ast[2*t];     tgt = ast[2*t+1]; }
    else if (t < 2*E_AST)          { int i = t - E_AST;         e = 1; src = ast[2*i+1]; tgt = ast[2*i]; }
    else if (t < 2*E_AST + E_MST)  { int i = t - 2*E_AST;       e = 2; src = mst[2*i];   tgt = mst[2*i+1]; }
    else                           { int i = t - 2*E_AST-E_MST; e = 3; src = mst[2*i+1]; tgt = mst[2*i]; }
}

__global__ void count4_kernel(const int* __restrict__ ast, const int* __restrict__ mst,
                              int* __restrict__ deg4) {
    int t = blockIdx.x * 256 + threadIdx.x;
    if (t >= E_TOT) return;
    int e, src, tgt; edge_decode(t, ast, mst, e, src, tgt);
    atomicAdd(&deg4[tgt * 4 + e], 1);
}

__global__ void scan1b(const int* __restrict__ deg, int* __restrict__ excl,
                       int* __restrict__ partial, int n) {
    __shared__ int sm[256];
    int t = threadIdx.x, b = blockIdx.x;
    int base = b * 2048 + t * 8;
    int v[8]; int s = 0;
    #pragma unroll
    for (int i = 0; i < 8; ++i) { v[i] = (base + i < n) ? deg[base + i] : 0; s += v[i]; }
    sm[t] = s;
    __syncthreads();
    for (int off = 1; off < 256; off <<= 1) {
        int x = (t >= off) ? sm[t - off] : 0;
        __syncthreads();
        sm[t] += x;
        __syncthreads();
    }
    int run = sm[t] - s;
    if (t == 255) partial[b] = sm[255];
    #pragma unroll
    for (int i = 0; i < 8; ++i) {
        if (base + i < n) { excl[base + i] = run; run += v[i]; }
    }
}

__global__ void scan2(int* __restrict__ partial, int nb) {
    __shared__ int sm[256];
    int t = threadIdx.x;
    int v = (t < nb) ? partial[t] : 0;
    sm[t] = v;
    __syncthreads();
    for (int off = 1; off < 256; off <<= 1) {
        int x = (t >= off) ? sm[t - off] : 0;
        __syncthreads();
        sm[t] += x;
        __syncthreads();
    }
    if (t < nb) partial[t] = sm[t] - v;
}

__global__ void scan3b(int* __restrict__ rp, const int* __restrict__ partial, int n, int etot) {
    int i = blockIdx.x * 256 + threadIdx.x;
    if (i < n) rp[i] += partial[i >> 11];
    if (i == n) rp[n] = etot;
}

__global__ void fill4_kernel(const int* __restrict__ ast, const int* __restrict__ mst,
                             const int* __restrict__ rp4, int* __restrict__ cnt4,
                             int* __restrict__ col) {
    int t = blockIdx.x * 256 + threadIdx.x;
    if (t >= E_TOT) return;
    int e, src, tgt; edge_decode(t, ast, mst, e, src, tgt);
    int key = tgt * 4 + e;
    int slot = rp4[key] + atomicAdd(&cnt4[key], 1);
    col[slot] = src;
}

// ---------------- weight prep: fp16 hi/lo splits ----------------
__global__ void prep_wmsg2(const float* __restrict__ W, ushort_t* __restrict__ hi,
                           ushort_t* __restrict__ lo) {
    int i = blockIdx.x * 256 + threadIdx.x;
    if (i >= 262144) return;
    fsplit(W[i], hi[i], lo[i]);
}

// B1 rows 2j/2j+1 = r_j/z_j over K=[Wih | Whh]; B2 rows 2j/2j+1 = inn_j(Wih,0) / hn_j(0,Whh)
__global__ void prep_B2(const float* __restrict__ Wih_a, const float* __restrict__ Wih_b,
                        const float* __restrict__ Whh,
                        ushort_t* __restrict__ B1h, ushort_t* __restrict__ B1l,
                        ushort_t* __restrict__ B2h, ushort_t* __restrict__ B2l) {
    int i = blockIdx.x * 256 + threadIdx.x;
    if (i >= 327680) return;
    int l, off, K;
    if (i < 65536)       { l = 0; off = 0;      K = 256; }
    else if (i < 163840) { l = 1; off = 65536;  K = 384; }
    else if (i < 229376) { l = 2; off = 163840; K = 256; }
    else                 { l = 3; off = 229376; K = 384; }
    int Kx = K - 128;
    const float* Wih = (l & 1) ? (Wih_b + (size_t)(l >> 1) * 384 * 256)
                               : (Wih_a + (size_t)(l >> 1) * 384 * 128);
    const float* WhhL = Whh + (size_t)l * 384 * 128;
    int rem = i - off;
    int row = rem / K, k = rem - row * K;
    int j = row >> 1, s = row & 1;
    int g1 = s * 128 + j;
    float v1 = (k < Kx) ? Wih[(size_t)g1 * Kx + k] : WhhL[(size_t)g1 * 128 + (k - Kx)];
    fsplit(v1, B1h[i], B1l[i]);
    int g2 = 256 + j;
    float v2;
    if (s == 0) v2 = (k < Kx) ? Wih[(size_t)g2 * Kx + k] : 0.f;
    else        v2 = (k < Kx) ? 0.f : WhhL[(size_t)g2 * 128 + (k - Kx)];
    fsplit(v2, B2h[i], B2l[i]);
}

// ---------------- msg GEMM: T[NN][128] = h @ W_e^T (A fp16-hi, W hi+lo: 2 products) ----------------
__global__ __launch_bounds__(256, 4) void msg_gemm(
    const float* __restrict__ h, const ushort_t* __restrict__ Whi,
    const ushort_t* __restrict__ Wlo, float* __restrict__ T)
{
    __shared__ ushort_t Ahi[128 * 64], Bs[128 * 64];
    const int tid = threadIdx.x, w = tid >> 6, l = tid & 63;
    const int m0 = blockIdx.x * 128;
    const int wm = w >> 1, wn = w & 1;
    f32x4 acc[4][4];
    #pragma unroll
    for (int a = 0; a < 4; ++a)
        #pragma unroll
        for (int b = 0; b < 4; ++b) acc[a][b] = (f32x4){0.f, 0.f, 0.f, 0.f};

    for (int kt = 0; kt < 2; ++kt) {
        const int kk = kt * 64;
        {
            int r = tid >> 1, half = tid & 1;
            int grow = m0 + r; if (grow >= NN) grow = NN - 1;
            const float* s = h + (size_t)grow * H + kk + half * 32;
            ushort_t hi32[32];
            #pragma unroll
            for (int q = 0; q < 8; ++q) {
                float4 v = *(const float4*)&s[q * 4];
                hi32[q*4+0] = f2h(v.x); hi32[q*4+1] = f2h(v.y);
                hi32[q*4+2] = f2h(v.z); hi32[q*4+3] = f2h(v.w);
            }
            #pragma unroll
            for (int gq = 0; gq < 4; ++gq) {
                int g = half * 4 + gq;
                int slot = g ^ (r & 7);
                *(us8*)&Ahi[r * 64 + slot * 8] = *(us8*)&hi32[gq * 8];
            }
        }
        #pragma unroll
        for (int q = 0; q < 4; ++q) {
            int row8 = w * 4 + q;
            const ushort_t* gs = Whi + (size_t)(row8 * 8 + (l >> 3)) * 128 + kk + ((l & 7) ^ (l >> 3)) * 8;
            GLD16(gs, &Bs[row8 * 512]);
        }
        __syncthreads();
        #pragma unroll
        for (int fk = 0; fk < 2; ++fk) {
            half8 ah[4], bh[4];
            #pragma unroll
            for (int fm = 0; fm < 4; ++fm) {
                int row = wm * 64 + fm * 16 + (l & 15);
                int slot = (fk * 4 + (l >> 4)) ^ (row & 7);
                ah[fm] = *(const half8*)&Ahi[row * 64 + slot * 8];
            }
            #pragma unroll
            for (int fn = 0; fn < 4; ++fn) {
                int row = wn * 64 + fn * 16 + (l & 15);
                int slot = (fk * 4 + (l >> 4)) ^ (row & 7);
                bh[fn] = *(const half8*)&Bs[row * 64 + slot * 8];
            }
            #pragma unroll
            for (int fm = 0; fm < 4; ++fm)
                #pragma unroll
                for (int fn = 0; fn < 4; ++fn)
                    acc[fm][fn] = __builtin_amdgcn_mfma_f32_16x16x32_f16(ah[fm], bh[fn], acc[fm][fn], 0, 0, 0);
        }
        __syncthreads();
        #pragma unroll
        for (int q = 0; q < 4; ++q) {
            int row8 = w * 4 + q;
            const ushort_t* gs = Wlo + (size_t)(row8 * 8 + (l >> 3)) * 128 + kk + ((l & 7) ^ (l >> 3)) * 8;
            GLD16(gs, &Bs[row8 * 512]);
        }
        __syncthreads();
        #pragma unroll
        for (int fk = 0; fk < 2; ++fk) {
            half8 ah[4], bl[4];
            #pragma unroll
            for (int fm = 0; fm < 4; ++fm) {
                int row = wm * 64 + fm * 16 + (l & 15);
                int slot = (fk * 4 + (l >> 4)) ^ (row & 7);
                ah[fm] = *(const half8*)&Ahi[row * 64 + slot * 8];
            }
            #pragma unroll
            for (int fn = 0; fn < 4; ++fn) {
                int row = wn * 64 + fn * 16 + (l & 15);
                int slot = (fk * 4 + (l >> 4)) ^ (row & 7);
                bl[fn] = *(const half8*)&Bs[row * 64 + slot * 8];
            }
            #pragma unroll
            for (int fm = 0; fm < 4; ++fm)
                #pragma unroll
                for (int fn = 0; fn < 4; ++fn)
                    acc[fm][fn] = __builtin_amdgcn_mfma_f32_16x16x32_f16(ah[fm], bl[fn], acc[fm][fn], 0, 0, 0);
        }
        __syncthreads();
    }
    #pragma unroll
    for (int fm = 0; fm < 4; ++fm)
        #pragma unroll
        for (int fn = 0; fn < 4; ++fn) {
            int cc = wn * 64 + fn * 16 + (l & 15);
            #pragma unroll
            for (int rg = 0; rg < 4; ++rg) {
                int row = m0 + wm * 64 + fm * 16 + (l >> 4) * 4 + rg;
                if (row < NN) T[(size_t)row * H + cc] = acc[fm][fn][rg];
            }
        }
}

// ---------------- gather over CSR quarter e: inc fp32 (+bias init at e==0) ----------------
__global__ void gather_q(const float* __restrict__ T, const int* __restrict__ rp4,
                         const int* __restrict__ col, const int* __restrict__ deg4,
                         const float* __restrict__ mb, float* __restrict__ inc, int e) {
    int wv = threadIdx.x >> 6, l = threadIdx.x & 63;
    int t = blockIdx.x * 4 + wv;
    if (t >= NN) return;
    int c2 = l * 2;
    float2 a;
    if (e == 0) {
        a = make_float2(0.f, 0.f);
        #pragma unroll
        for (int e4 = 0; e4 < 4; ++e4) {
            float d = (float)deg4[t * 4 + e4];
            a.x += d * mb[e4 * H + c2];
            a.y += d * mb[e4 * H + c2 + 1];
        }
    } else {
        a = *(const float2*)&inc[(size_t)t * H + c2];
    }
    int s0 = rp4[4 * t + e], s1 = rp4[4 * t + e + 1];
    for (int s = s0; s < s1; ++s) {
        float2 v = *(const float2*)&T[(size_t)col[s] * H + c2];
        a.x += v.x; a.y += v.y;
    }
    *(float2*)&inc[(size_t)t * H + c2] = a;
}

// ---------------- gate GEMM: 64x256 tile, A fp16-hi only, B hi+lo ----------------
// MODE 1: r,z -> rzhi pairs + zlo.  MODE 2: inn/hn + GRU epilogue -> h fp32 in place.
// CFG 0: [inc,h] K=256; 1: [inc,emb,h] K=384; 2: [inc,s1,h] K=384
template<int MODE, int CFG>
__global__ __launch_bounds__(256, 4) void gate_gemm(
    const float* __restrict__ inc, float* __restrict__ h,
    const ushort_t* __restrict__ s1h, const float* __restrict__ emb, const int* __restrict__ ids,
    const ushort_t* __restrict__ Bhi, const ushort_t* __restrict__ Blo,
    ushort_t* __restrict__ rzhi, ushort_t* __restrict__ zlo,
    const float* __restrict__ bihL, const float* __restrict__ bhhL)
{
    constexpr int NPARTS = (CFG == 0) ? 2 : 3;
    constexpr int K = NPARTS * 128;
    __shared__ ushort_t Ahi[64 * 64];
    __shared__ ushort_t Bs[256 * 64];
    const int tid = threadIdx.x, w = tid >> 6, l = tid & 63;
    const int m0 = blockIdx.x * 64;
    f32x4 acc[4][4];
    #pragma unroll
    for (int a = 0; a < 4; ++a)
        #pragma unroll
        for (int b = 0; b < 4; ++b) acc[a][b] = (f32x4){0.f, 0.f, 0.f, 0.f};

    for (int kt = 0; kt < NPARTS * 2; ++kt) {
        const int p = kt >> 1;
        const int kk = (kt & 1) * 64;
        const int kb = p * 128 + kk;
        const bool isS1mid = (CFG == 2) && (p == 1);

        if (!isS1mid) {
            // fp32 source -> fp16-hi staging; coalesced: 4 lanes per row, 64B each
            int r = tid >> 2, half = tid & 3;
            int grow = m0 + r; if (grow >= NN) grow = NN - 1;
            const float* src;
            if (p == 0)               src = inc + (size_t)grow * H;
            else if (p == NPARTS - 1) src = h + (size_t)grow * H;
            else                      src = emb + (size_t)ids[grow] * H;   // CFG==1 middle
            src += kk + half * 16;
            ushort_t hi16[16];
            #pragma unroll
            for (int q = 0; q < 4; ++q) {
                float4 v = *(const float4*)&src[q * 4];
                hi16[q*4+0] = f2h(v.x); hi16[q*4+1] = f2h(v.y);
                hi16[q*4+2] = f2h(v.z); hi16[q*4+3] = f2h(v.w);
            }
            #pragma unroll
            for (int gq = 0; gq < 2; ++gq) {
                int slot = (half * 2 + gq) ^ (r & 7);
                *(us8*)&Ahi[r * 64 + slot * 8] = *(us8*)&hi16[gq * 8];
            }
        } else {
            // CFG==2 middle: s1 fp16 single via GLD16
            #pragma unroll
            for (int q = 0; q < 2; ++q) {
                int row8 = w * 2 + q;
                int row = row8 * 8 + (l >> 3);
                int grow = m0 + row; if (grow >= NN) grow = NN - 1;
                const ushort_t* gs = s1h + (size_t)grow * H + kk + ((l & 7) ^ (l >> 3)) * 8;
                GLD16(gs, &Ahi[row8 * 512]);
            }
        }
        #pragma unroll
        for (int q = 0; q < 8; ++q) {
            int row8 = w * 8 + q;
            const ushort_t* gs = Bhi + (size_t)(row8 * 8 + (l >> 3)) * K + kb + ((l & 7) ^ (l >> 3)) * 8;
            GLD16(gs, &Bs[row8 * 512]);
        }
        __syncthreads();
        #pragma unroll
        for (int fk = 0; fk < 2; ++fk) {
            half8 ah[4], bh[4];
            #pragma unroll
            for (int fm = 0; fm < 4; ++fm) {
                int row = fm * 16 + (l & 15);
                int slot = (fk * 4 + (l >> 4)) ^ (row & 7);
                ah[fm] = *(const half8*)&Ahi[row * 64 + slot * 8];
            }
            #pragma unroll
            for (int fn = 0; fn < 4; ++fn) {
                int row = w * 64 + fn * 16 + (l & 15);
                int slot = (fk * 4 + (l >> 4)) ^ (row & 7);
                bh[fn] = *(const half8*)&Bs[row * 64 + slot * 8];
            }
            #pragma unroll
            for (int fm = 0; fm < 4; ++fm)
                #pragma unroll
                for (int fn = 0; fn < 4; ++fn)
                    acc[fm][fn] = __builtin_amdgcn_mfma_f32_16x16x32_f16(ah[fm], bh[fn], acc[fm][fn], 0, 0, 0);
        }
        __syncthreads();
        #pragma unroll
        for (int q = 0; q < 8; ++q) {
            int row8 = w * 8 + q;
            const ushort_t* gs = Blo + (size_t)(row8 * 8 + (l >> 3)) * K + kb + ((l & 7) ^ (l >> 3)) * 8;
            GLD16(gs, &Bs[row8 * 512]);
        }
        __syncthreads();
        #pragma unroll
        for (int fk = 0; fk < 2; ++fk) {
            half8 ah[4], bl[4];
            #pragma unroll
            for (int fm = 0; fm < 4; ++fm) {
                int row = fm * 16 + (l & 15);
                int slot = (fk * 4 + (l >> 4)) ^ (row & 7);
                ah[fm] = *(const half8*)&Ahi[row * 64 + slot * 8];
            }
            #pragma unroll
            for (int fn = 0; fn < 4; ++fn) {
                int row = w * 64 + fn * 16 + (l & 15);
                int slot = (fk * 4 + (l >> 4)) ^ (row & 7);
                bl[fn] = *(const half8*)&Bs[row * 64 + slot * 8];
            }
            #pragma unroll
            for (int fm = 0; fm < 4; ++fm)
                #pragma unroll
                for (int fn = 0; fn < 4; ++fn)
                    acc[fm][fn] = __builtin_amdgcn_mfma_f32_16x16x32_f16(ah[fm], bl[fn], acc[fm][fn], 0, 0, 0);
        }
        __syncthreads();
    }

    // epilogue
    #pragma unroll
    for (int fm = 0; fm < 4; ++fm)
        #pragma unroll
        for (int fn = 0; fn < 4; ++fn) {
            int cc = w * 64 + fn * 16 + (l & 15);
            int j = cc >> 1, s = cc & 1;
            #pragma unroll
            for (int rg = 0; rg < 4; ++rg) {
                int row = m0 + fm * 16 + (l >> 4) * 4 + rg;
                float v = acc[fm][fn][rg];
                if (MODE == 1) {
                    float pre = v + bihL[s * 128 + j] + bhhL[s * 128 + j];
                    float g = 1.f / (1.f + __expf(-pre));
                    unsigned short gh = f2h(g);
                    int ot = __shfl_xor((int)gh, 1);
                    if (row < NN) {
                        if (s == 0)
                            *(unsigned*)&rzhi[(size_t)row * 256 + cc] =
                                (unsigned)gh | ((unsigned)(unsigned short)ot << 16);
                        else
                            zlo[(size_t)row * H + j] = f2h(g - h2f(gh));
                    }
                } else {
                    float self = v + (s ? bhhL[256 + j] : bihL[256 + j]);
                    float other = __shfl_xor(self, 1);
                    if (s == 0 && row < NN) {
                        unsigned rzp = *(const unsigned*)&rzhi[(size_t)row * 256 + cc];
                        float r = h2f((unsigned short)(rzp & 0xffff));
                        float z = h2f((unsigned short)(rzp >> 16)) + h2f(zlo[(size_t)row * H + j]);
                        float n = tanhf(self + r * other);
                        float hold = h[(size_t)row * H + j];
                        h[(size_t)row * H + j] = (1.f - z) * n + z * hold;
                    }
                }
            }
        }
}

// ---------------- s1 snapshot: h fp32 -> fp16 ----------------
__global__ void h2h16(const float* __restrict__ h, ushort_t* __restrict__ s1h) {
    int g = blockIdx.x * 256 + threadIdx.x;
    if (g >= NN * 64) return;
    float2 v = *(const float2*)&h[(size_t)g * 2];
    unsigned pk = (unsigned)f2h(v.x) | ((unsigned)f2h(v.y) << 16);
    *(unsigned*)&s1h[(size_t)g * 2] = pk;
}

// ---------------- output gathers ----------------
__global__ void out_gather(const float* __restrict__ h, const int* __restrict__ idx,
                           float* __restrict__ out, int n) {
    int g = blockIdx.x * 256 + threadIdx.x;
    if (g >= n * 64) return;
    int v = g >> 6, j2 = (g & 63) << 1;
    *(float2*)&out[(size_t)v * H + j2] = *(const float2*)&h[(size_t)idx[v] * H + j2];
}

extern "C" void kernel_launch(void* const* d_in, const int* in_sizes, int n_in,
                              void* d_out, int out_size, void* d_ws, size_t ws_size,
                              hipStream_t stream) {
    const int*   ids    = (const int*)d_in[0];
    const int*   ast    = (const int*)d_in[1];
    const int*   mst    = (const int*)d_in[2];
    const int*   varpos = (const int*)d_in[3];
    const int*   predid = (const int*)d_in[4];
    const float* emb    = (const float*)d_in[5];
    const float* msg_W  = (const float*)d_in[6];
    const float* msg_b  = (const float*)d_in[7];
    const float* Wih_a  = (const float*)d_in[8];
    const float* Wih_b  = (const float*)d_in[9];
    const float* Whh    = (const float*)d_in[10];
    const float* bih    = (const float*)d_in[11];
    const float* bhh    = (const float*)d_in[12];

    float* out = (float*)d_out;
    float* h   = out;                              // h fp32 lives in d_out

    int* ibase = (int*)(out + NH);
    int* deg4  = ibase;                            // 400000
    int* rp4   = ibase + 400000;                   // 400001
    int* cnt4  = ibase + 800001;                   // 400000
    int* col   = ibase + 1200001;                  // 240000
    int* part  = ibase + 1440001;                  // 256
    ushort_t* WT   = (ushort_t*)(ibase + 1500000);
    ushort_t* wmh  = WT;                           // 262144
    ushort_t* wml  = WT + 262144;
    ushort_t* B1h  = WT + 524288;                  // 327680
    ushort_t* B1l  = WT + 851968;
    ushort_t* B2h  = WT + 1179648;
    ushort_t* B2l  = WT + 1507328;                 // end 1835008 ush

    if (ws_size < (size_t)153600000) return;
    char* wsb = (char*)d_ws;
    float*    inc  = (float*)wsb;                          // 51.2 MB [NN][128]
    ushort_t* s1h  = (ushort_t*)(wsb + 51200000);          // 25.6 MB
    float*    T    = (float*)(wsb + 76800000);             // 51.2 MB (msg phase)
    ushort_t* rzhi = (ushort_t*)(wsb + 76800000);          // 51.2 MB (gate phase, shares T)
    ushort_t* zlo  = (ushort_t*)(wsb + 128000000);         // 25.6 MB

    embed_kernel<<<25000, 256, 0, stream>>>(ids, emb, h);

    hipMemsetAsync(deg4, 0, N4 * sizeof(int), stream);
    hipMemsetAsync(cnt4, 0, N4 * sizeof(int), stream);
    count4_kernel<<<(E_TOT + 255) / 256, 256, 0, stream>>>(ast, mst, deg4);
    scan1b<<<196, 256, 0, stream>>>(deg4, rp4, part, N4);
    scan2<<<1, 256, 0, stream>>>(part, 196);
    scan3b<<<1563, 256, 0, stream>>>(rp4, part, N4, E_TOT);
    fill4_kernel<<<(E_TOT + 255) / 256, 256, 0, stream>>>(ast, mst, rp4, cnt4, col);
    prep_wmsg2<<<1024, 256, 0, stream>>>(msg_W, wmh, wml);
    prep_B2<<<1280, 256, 0, stream>>>(Wih_a, Wih_b, Whh, B1h, B1l, B2h, B2l);

    const int LT[4] = {5, 2, 5, 2};
    const int Boff[4] = {0, 65536, 163840, 229376};
    for (int layer = 0; layer < 4; ++layer) {
        const float* bihL = bih + layer * 384;
        const float* bhhL = bhh + layer * 384;
        const float* mbL  = msg_b + (size_t)layer * 512;
        const ushort_t* B1hL = B1h + Boff[layer];
        const ushort_t* B1lL = B1l + Boff[layer];
        const ushort_t* B2hL = B2h + Boff[layer];
        const ushort_t* B2lL = B2l + Boff[layer];

        for (int ts = 0; ts < LT[layer]; ++ts) {
            for (int e = 0; e < 4; ++e) {
                const ushort_t* WhiE = wmh + ((size_t)layer * 4 + e) * 16384;
                const ushort_t* WloE = wml + ((size_t)layer * 4 + e) * 16384;
                msg_gemm<<<782, 256, 0, stream>>>(h, WhiE, WloE, T);
                gather_q<<<25000, 256, 0, stream>>>(T, rp4, col, deg4, mbL, inc, e);
            }
            if (layer == 0 || layer == 2) {
                gate_gemm<1,0><<<1563, 256, 0, stream>>>(inc, h, s1h, emb, ids, B1hL, B1lL, rzhi, zlo, bihL, bhhL);
                gate_gemm<2,0><<<1563, 256, 0, stream>>>(inc, h, s1h, emb, ids, B2hL, B2lL, rzhi, zlo, bihL, bhhL);
            } else if (layer == 1) {
                gate_gemm<1,1><<<1563, 256, 0, stream>>>(inc, h, s1h, emb, ids, B1hL, B1lL, rzhi, zlo, bihL, bhhL);
                gate_gemm<2,1><<<1563, 256, 0, stream>>>(inc, h, s1h, emb, ids, B2hL, B2lL, rzhi, zlo, bihL, bhhL);
            } else {
                gate_gemm<1,2><<<1563, 256, 0, stream>>>(inc, h, s1h, emb, ids, B1hL, B1lL, rzhi, zlo, bihL, bhhL);
                gate_gemm<2,2><<<1563, 256, 0, stream>>>(inc, h, s1h, emb, ids, B2hL, B2lL, rzhi, zlo, bihL, bhhL);
            }
        }
        if (layer == 0)
            h2h16<<<25000, 256, 0, stream>>>(h, s1h);
    }

    out_gather<<<(NV * 64 + 255) / 256, 256, 0, stream>>>(h, varpos, out + NH, NV);
    out_gather<<<(NP * 64 + 255) / 256, 256, 0, stream>>>(h, predid, out + NH + (size_t)NV * H, NP);
}

// Round 9
// 5043.035 us; speedup vs baseline: 1.6673x; 1.3733x over previous
//
#include <hip/hip_runtime.h>
#include <math.h>

#define H 128
#define NN 100000
#define E_AST 100000
#define E_MST 20000
#define E_TOT 240000
#define NV 30000
#define NP 8000
#define N4 400000
#define NH 12800000   // NN * H
#define VOCAB 15128

typedef unsigned short ushort_t;
typedef __attribute__((ext_vector_type(8))) unsigned short us8;
typedef _Float16 half8 __attribute__((ext_vector_type(8)));
typedef __attribute__((ext_vector_type(4))) float f32x4;

__device__ __forceinline__ unsigned short f2h(float f) {
    _Float16 h = (_Float16)f;
    return __builtin_bit_cast(unsigned short, h);
}
__device__ __forceinline__ float h2f(unsigned short u) {
    return (float)__builtin_bit_cast(_Float16, u);
}
__device__ __forceinline__ void fsplit(float x, unsigned short& hi, unsigned short& lo) {
    _Float16 a = (_Float16)x;
    _Float16 b = (_Float16)(x - (float)a);
    hi = __builtin_bit_cast(unsigned short, a);
    lo = __builtin_bit_cast(unsigned short, b);
}

#define GLD16(gsrc, ldst) __builtin_amdgcn_global_load_lds( \
    (const __attribute__((address_space(1))) unsigned int*)(gsrc), \
    (__attribute__((address_space(3))) unsigned int*)(ldst), 16, 0, 0)

// ---------------- embedding -> h fp32 + h16 ----------------
__global__ void embed_kernel(const int* __restrict__ ids, const float* __restrict__ emb,
                             float* __restrict__ h, ushort_t* __restrict__ h16) {
    int g = blockIdx.x * 256 + threadIdx.x;
    if (g >= NN * 64) return;
    int i = g >> 6, j2 = (g & 63) << 1;
    float2 v = *(const float2*)&emb[(size_t)ids[i] * H + j2];
    *(float2*)&h[(size_t)i * H + j2] = v;
    unsigned pk = (unsigned)f2h(v.x) | ((unsigned)f2h(v.y) << 16);
    *(unsigned*)&h16[(size_t)i * H + j2] = pk;
}

// ---------------- CSR build over keys (tgt*4 + e), payload src ----------------
__device__ inline void edge_decode(int t, const int* __restrict__ ast, const int* __restrict__ mst,
                                   int& e, int& src, int& tgt) {
    if (t < E_AST)                 { e = 0; src = ast[2*t];     tgt = ast[2*t+1]; }
    else if (t < 2*E_AST)          { int i = t - E_AST;         e = 1; src = ast[2*i+1]; tgt = ast[2*i]; }
    else if (t < 2*E_AST + E_MST)  { int i = t - 2*E_AST;       e = 2; src = mst[2*i];   tgt = mst[2*i+1]; }
    else                           { int i = t - 2*E_AST-E_MST; e = 3; src = mst[2*i+1]; tgt = mst[2*i]; }
}

__global__ void count4_kernel(const int* __restrict__ ast, const int* __restrict__ mst,
                              int* __restrict__ deg4) {
    int t = blockIdx.x * 256 + threadIdx.x;
    if (t >= E_TOT) return;
    int e, src, tgt; edge_decode(t, ast, mst, e, src, tgt);
    atomicAdd(&deg4[tgt * 4 + e], 1);
}

__global__ void scan1b(const int* __restrict__ deg, int* __restrict__ excl,
                       int* __restrict__ partial, int n) {
    __shared__ int sm[256];
    int t = threadIdx.x, b = blockIdx.x;
    int base = b * 2048 + t * 8;
    int v[8]; int s = 0;
    #pragma unroll
    for (int i = 0; i < 8; ++i) { v[i] = (base + i < n) ? deg[base + i] : 0; s += v[i]; }
    sm[t] = s;
    __syncthreads();
    for (int off = 1; off < 256; off <<= 1) {
        int x = (t >= off) ? sm[t - off] : 0;
        __syncthreads();
        sm[t] += x;
        __syncthreads();
    }
    int run = sm[t] - s;
    if (t == 255) partial[b] = sm[255];
    #pragma unroll
    for (int i = 0; i < 8; ++i) {
        if (base + i < n) { excl[base + i] = run; run += v[i]; }
    }
}

__global__ void scan2(int* __restrict__ partial, int nb) {
    __shared__ int sm[256];
    int t = threadIdx.x;
    int v = (t < nb) ? partial[t] : 0;
    sm[t] = v;
    __syncthreads();
    for (int off = 1; off < 256; off <<= 1) {
        int x = (t >= off) ? sm[t - off] : 0;
        __syncthreads();
        sm[t] += x;
        __syncthreads();
    }
    if (t < nb) partial[t] = sm[t] - v;
}

__global__ void scan3b(int* __restrict__ rp, const int* __restrict__ partial, int n, int etot) {
    int i = blockIdx.x * 256 + threadIdx.x;
    if (i < n) rp[i] += partial[i >> 11];
    if (i == n) rp[n] = etot;
}

__global__ void fill4_kernel(const int* __restrict__ ast, const int* __restrict__ mst,
                             const int* __restrict__ rp4, int* __restrict__ cnt4,
                             int* __restrict__ col) {
    int t = blockIdx.x * 256 + threadIdx.x;
    if (t >= E_TOT) return;
    int e, src, tgt; edge_decode(t, ast, mst, e, src, tgt);
    int key = tgt * 4 + e;
    int slot = rp4[key] + atomicAdd(&cnt4[key], 1);
    col[slot] = src;
}

// ---------------- weight prep ----------------
__global__ void prep_wmsg2(const float* __restrict__ W, ushort_t* __restrict__ hi,
                           ushort_t* __restrict__ lo) {
    int i = blockIdx.x * 256 + threadIdx.x;
    if (i >= 262144) return;
    fsplit(W[i], hi[i], lo[i]);
}

__global__ void prep_emb16(const float* __restrict__ emb, ushort_t* __restrict__ emb16) {
    int i = blockIdx.x * 256 + threadIdx.x;
    if (i >= VOCAB * H) return;
    emb16[i] = f2h(emb[i]);
}

// B1 rows 2j/2j+1 = r_j/z_j over K=[Wih | Whh]; B2 rows 2j/2j+1 = inn_j(Wih,0) / hn_j(0,Whh)
__global__ void prep_B2(const float* __restrict__ Wih_a, const float* __restrict__ Wih_b,
                        const float* __restrict__ Whh,
                        ushort_t* __restrict__ B1h, ushort_t* __restrict__ B1l,
                        ushort_t* __restrict__ B2h, ushort_t* __restrict__ B2l) {
    int i = blockIdx.x * 256 + threadIdx.x;
    if (i >= 327680) return;
    int l, off, K;
    if (i < 65536)       { l = 0; off = 0;      K = 256; }
    else if (i < 163840) { l = 1; off = 65536;  K = 384; }
    else if (i < 229376) { l = 2; off = 163840; K = 256; }
    else                 { l = 3; off = 229376; K = 384; }
    int Kx = K - 128;
    const float* Wih = (l & 1) ? (Wih_b + (size_t)(l >> 1) * 384 * 256)
                               : (Wih_a + (size_t)(l >> 1) * 384 * 128);
    const float* WhhL = Whh + (size_t)l * 384 * 128;
    int rem = i - off;
    int row = rem / K, k = rem - row * K;
    int j = row >> 1, s = row & 1;
    int g1 = s * 128 + j;
    float v1 = (k < Kx) ? Wih[(size_t)g1 * Kx + k] : WhhL[(size_t)g1 * 128 + (k - Kx)];
    fsplit(v1, B1h[i], B1l[i]);
    int g2 = 256 + j;
    float v2;
    if (s == 0) v2 = (k < Kx) ? Wih[(size_t)g2 * Kx + k] : 0.f;
    else        v2 = (k < Kx) ? 0.f : WhhL[(size_t)g2 * 128 + (k - Kx)];
    fsplit(v2, B2h[i], B2l[i]);
}

// ---------------- msg GEMM: T16[NN][128] = h16 @ W_e^T (W hi+lo: 2 products) ----------------
__global__ __launch_bounds__(256, 4) void msg_gemm(
    const ushort_t* __restrict__ h16, const ushort_t* __restrict__ Whi,
    const ushort_t* __restrict__ Wlo, ushort_t* __restrict__ T16)
{
    __shared__ ushort_t Ah[128 * 64], Bs[128 * 64];
    const int tid = threadIdx.x, w = tid >> 6, l = tid & 63;
    const int m0 = blockIdx.x * 128;
    const int wm = w >> 1, wn = w & 1;
    const int lr8 = l >> 3, lslot = (l & 7) ^ lr8;
    f32x4 acc[4][4];
    #pragma unroll
    for (int a = 0; a < 4; ++a)
        #pragma unroll
        for (int b = 0; b < 4; ++b) acc[a][b] = (f32x4){0.f, 0.f, 0.f, 0.f};

    for (int kt = 0; kt < 2; ++kt) {
        const int kk = kt * 64;
        #pragma unroll
        for (int q = 0; q < 4; ++q) {
            int row8 = w * 4 + q;
            int grow = m0 + row8 * 8 + lr8; if (grow >= NN) grow = NN - 1;
            GLD16(h16 + (size_t)grow * H + kk + lslot * 8, &Ah[row8 * 512]);
        }
        #pragma unroll
        for (int q = 0; q < 4; ++q) {
            int row8 = w * 4 + q;
            GLD16(Whi + (size_t)(row8 * 8 + lr8) * 128 + kk + lslot * 8, &Bs[row8 * 512]);
        }
        __syncthreads();
        #pragma unroll
        for (int fk = 0; fk < 2; ++fk) {
            half8 av[4], bv[4];
            #pragma unroll
            for (int fm = 0; fm < 4; ++fm) {
                int row = wm * 64 + fm * 16 + (l & 15);
                int slot = (fk * 4 + (l >> 4)) ^ (row & 7);
                av[fm] = *(const half8*)&Ah[row * 64 + slot * 8];
            }
            #pragma unroll
            for (int fn = 0; fn < 4; ++fn) {
                int row = wn * 64 + fn * 16 + (l & 15);
                int slot = (fk * 4 + (l >> 4)) ^ (row & 7);
                bv[fn] = *(const half8*)&Bs[row * 64 + slot * 8];
            }
            #pragma unroll
            for (int fm = 0; fm < 4; ++fm)
                #pragma unroll
                for (int fn = 0; fn < 4; ++fn)
                    acc[fm][fn] = __builtin_amdgcn_mfma_f32_16x16x32_f16(av[fm], bv[fn], acc[fm][fn], 0, 0, 0);
        }
        __syncthreads();
        #pragma unroll
        for (int q = 0; q < 4; ++q) {
            int row8 = w * 4 + q;
            GLD16(Wlo + (size_t)(row8 * 8 + lr8) * 128 + kk + lslot * 8, &Bs[row8 * 512]);
        }
        __syncthreads();
        #pragma unroll
        for (int fk = 0; fk < 2; ++fk) {
            half8 av[4], bv[4];
            #pragma unroll
            for (int fm = 0; fm < 4; ++fm) {
                int row = wm * 64 + fm * 16 + (l & 15);
                int slot = (fk * 4 + (l >> 4)) ^ (row & 7);
                av[fm] = *(const half8*)&Ah[row * 64 + slot * 8];
            }
            #pragma unroll
            for (int fn = 0; fn < 4; ++fn) {
                int row = wn * 64 + fn * 16 + (l & 15);
                int slot = (fk * 4 + (l >> 4)) ^ (row & 7);
                bv[fn] = *(const half8*)&Bs[row * 64 + slot * 8];
            }
            #pragma unroll
            for (int fm = 0; fm < 4; ++fm)
                #pragma unroll
                for (int fn = 0; fn < 4; ++fn)
                    acc[fm][fn] = __builtin_amdgcn_mfma_f32_16x16x32_f16(av[fm], bv[fn], acc[fm][fn], 0, 0, 0);
        }
        __syncthreads();
    }
    // epilogue: fp16 pack via neighbor-lane shfl, u32 stores from even lanes
    #pragma unroll
    for (int fm = 0; fm < 4; ++fm)
        #pragma unroll
        for (int fn = 0; fn < 4; ++fn) {
            int cc = wn * 64 + fn * 16 + (l & 15);
            #pragma unroll
            for (int rg = 0; rg < 4; ++rg) {
                int row = m0 + wm * 64 + fm * 16 + (l >> 4) * 4 + rg;
                unsigned short us = f2h(acc[fm][fn][rg]);
                int prt = __shfl_xor((int)us, 1);
                if (!(l & 1) && row < NN) {
                    unsigned pk = (unsigned)us | ((unsigned)(unsigned short)prt << 16);
                    *(unsigned*)&T16[(size_t)row * H + cc] = pk;
                }
            }
        }
}

// ---------------- gather pair (e=base, base+1) from fp16 T quarters into inc16 ----------------
__global__ void gather2(const ushort_t* __restrict__ Tq, const int* __restrict__ rp4,
                        const int* __restrict__ col, const int* __restrict__ deg4,
                        const float* __restrict__ mb, ushort_t* __restrict__ inc16, int base) {
    int wv = threadIdx.x >> 6, l = threadIdx.x & 63;
    int t = blockIdx.x * 4 + wv;
    if (t >= NN) return;
    int c2 = l * 2;
    float a0, a1;
    if (base == 0) {
        a0 = 0.f; a1 = 0.f;
        #pragma unroll
        for (int e4 = 0; e4 < 4; ++e4) {
            float d = (float)deg4[t * 4 + e4];
            a0 += d * mb[e4 * H + c2];
            a1 += d * mb[e4 * H + c2 + 1];
        }
    } else {
        unsigned pk = *(const unsigned*)&inc16[(size_t)t * H + c2];
        a0 = h2f((unsigned short)(pk & 0xffff));
        a1 = h2f((unsigned short)(pk >> 16));
    }
    #pragma unroll
    for (int ep = 0; ep < 2; ++ep) {
        int e = base + ep;
        int s0 = rp4[4 * t + e], s1 = rp4[4 * t + e + 1];
        const ushort_t* Tb = Tq + (size_t)ep * NH;
        for (int s = s0; s < s1; ++s) {
            unsigned vv = *(const unsigned*)&Tb[(size_t)col[s] * H + c2];
            a0 += h2f((unsigned short)(vv & 0xffff));
            a1 += h2f((unsigned short)(vv >> 16));
        }
    }
    unsigned pk = (unsigned)f2h(a0) | ((unsigned)f2h(a1) << 16);
    *(unsigned*)&inc16[(size_t)t * H + c2] = pk;
}

// ---------------- gate GEMM: 64x256 tile, all-A via GLD16 from fp16 buffers ----------------
// MODE 1: r,z -> rzhi pairs + zlo.  MODE 2: inn/hn + GRU epilogue -> h32 + h16 in place.
// CFG 0: [inc,h] K=256; 1: [inc,emb16,h] K=384; 2: [inc,s1h,h] K=384
template<int MODE, int CFG>
__global__ __launch_bounds__(256, 4) void gate_gemm(
    const ushort_t* __restrict__ inc16, float* __restrict__ h, ushort_t* __restrict__ h16,
    const ushort_t* __restrict__ s1h, const ushort_t* __restrict__ emb16, const int* __restrict__ ids,
    const ushort_t* __restrict__ Bhi, const ushort_t* __restrict__ Blo,
    ushort_t* __restrict__ rzhi, ushort_t* __restrict__ zlo,
    const float* __restrict__ bihL, const float* __restrict__ bhhL)
{
    constexpr int NPARTS = (CFG == 0) ? 2 : 3;
    constexpr int K = NPARTS * 128;
    __shared__ ushort_t Ah[64 * 64];
    __shared__ ushort_t Bs[256 * 64];
    const int tid = threadIdx.x, w = tid >> 6, l = tid & 63;
    const int m0 = blockIdx.x * 64;
    const int lr8 = l >> 3, lslot = (l & 7) ^ lr8;
    f32x4 acc[4][4];
    #pragma unroll
    for (int a = 0; a < 4; ++a)
        #pragma unroll
        for (int b = 0; b < 4; ++b) acc[a][b] = (f32x4){0.f, 0.f, 0.f, 0.f};

    for (int kt = 0; kt < NPARTS * 2; ++kt) {
        const int p = kt >> 1;
        const int kk = (kt & 1) * 64;
        const int kb = p * 128 + kk;

        // A stage: 2 GLD16 per warp from the fp16 source for part p
        #pragma unroll
        for (int q = 0; q < 2; ++q) {
            int row8 = w * 2 + q;
            int grow = m0 + row8 * 8 + lr8; if (grow >= NN) grow = NN - 1;
            const ushort_t* sb;
            if (p == 0)               sb = inc16 + (size_t)grow * H;
            else if (p == NPARTS - 1) sb = h16 + (size_t)grow * H;
            else if (CFG == 1)        sb = emb16 + (size_t)ids[grow] * H;
            else                      sb = s1h + (size_t)grow * H;
            GLD16(sb + kk + lslot * 8, &Ah[row8 * 512]);
        }
        #pragma unroll
        for (int q = 0; q < 8; ++q) {
            int row8 = w * 8 + q;
            GLD16(Bhi + (size_t)(row8 * 8 + lr8) * K + kb + lslot * 8, &Bs[row8 * 512]);
        }
        __syncthreads();
        #pragma unroll
        for (int fk = 0; fk < 2; ++fk) {
            half8 av[4], bv[4];
            #pragma unroll
            for (int fm = 0; fm < 4; ++fm) {
                int row = fm * 16 + (l & 15);
                int slot = (fk * 4 + (l >> 4)) ^ (row & 7);
                av[fm] = *(const half8*)&Ah[row * 64 + slot * 8];
            }
            #pragma unroll
            for (int fn = 0; fn < 4; ++fn) {
                int row = w * 64 + fn * 16 + (l & 15);
                int slot = (fk * 4 + (l >> 4)) ^ (row & 7);
                bv[fn] = *(const half8*)&Bs[row * 64 + slot * 8];
            }
            #pragma unroll
            for (int fm = 0; fm < 4; ++fm)
                #pragma unroll
                for (int fn = 0; fn < 4; ++fn)
                    acc[fm][fn] = __builtin_amdgcn_mfma_f32_16x16x32_f16(av[fm], bv[fn], acc[fm][fn], 0, 0, 0);
        }
        __syncthreads();
        #pragma unroll
        for (int q = 0; q < 8; ++q) {
            int row8 = w * 8 + q;
            GLD16(Blo + (size_t)(row8 * 8 + lr8) * K + kb + lslot * 8, &Bs[row8 * 512]);
        }
        __syncthreads();
        #pragma unroll
        for (int fk = 0; fk < 2; ++fk) {
            half8 av[4], bv[4];
            #pragma unroll
            for (int fm = 0; fm < 4; ++fm) {
                int row = fm * 16 + (l & 15);
                int slot = (fk * 4 + (l >> 4)) ^ (row & 7);
                av[fm] = *(const half8*)&Ah[row * 64 + slot * 8];
            }
            #pragma unroll
            for (int fn = 0; fn < 4; ++fn) {
                int row = w * 64 + fn * 16 + (l & 15);
                int slot = (fk * 4 + (l >> 4)) ^ (row & 7);
                bv[fn] = *(const half8*)&Bs[row * 64 + slot * 8];
            }
            #pragma unroll
            for (int fm = 0; fm < 4; ++fm)
                #pragma unroll
                for (int fn = 0; fn < 4; ++fn)
                    acc[fm][fn] = __builtin_amdgcn_mfma_f32_16x16x32_f16(av[fm], bv[fn], acc[fm][fn], 0, 0, 0);
        }
        __syncthreads();
    }

    // epilogue
    #pragma unroll
    for (int fm = 0; fm < 4; ++fm)
        #pragma unroll
        for (int fn = 0; fn < 4; ++fn) {
            int cc = w * 64 + fn * 16 + (l & 15);
            int j = cc >> 1, s = cc & 1;
            #pragma unroll
            for (int rg = 0; rg < 4; ++rg) {
                int row = m0 + fm * 16 + (l >> 4) * 4 + rg;
                float v = acc[fm][fn][rg];
                if (MODE == 1) {
                    float pre = v + bihL[s * 128 + j] + bhhL[s * 128 + j];
                    float g = 1.f / (1.f + __expf(-pre));
                    unsigned short gh = f2h(g);
                    int ot = __shfl_xor((int)gh, 1);
                    if (row < NN) {
                        if (s == 0)
                            *(unsigned*)&rzhi[(size_t)row * 256 + cc] =
                                (unsigned)gh | ((unsigned)(unsigned short)ot << 16);
                        else
                            zlo[(size_t)row * H + j] = f2h(g - h2f(gh));
                    }
                } else {
                    float self = v + (s ? bhhL[256 + j] : bihL[256 + j]);
                    float other = __shfl_xor(self, 1);
                    if (s == 0 && row < NN) {
                        unsigned rzp = *(const unsigned*)&rzhi[(size_t)row * 256 + cc];
                        float r = h2f((unsigned short)(rzp & 0xffff));
                        float z = h2f((unsigned short)(rzp >> 16)) + h2f(zlo[(size_t)row * H + j]);
                        float n = tanhf(self + r * other);
                        float hold = h[(size_t)row * H + j];
                        float o = (1.f - z) * n + z * hold;
                        h[(size_t)row * H + j] = o;
                        h16[(size_t)row * H + j] = f2h(o);
                    }
                }
            }
        }
}

// ---------------- output gathers ----------------
__global__ void out_gather(const float* __restrict__ h, const int* __restrict__ idx,
                           float* __restrict__ out, int n) {
    int g = blockIdx.x * 256 + threadIdx.x;
    if (g >= n * 64) return;
    int v = g >> 6, j2 = (g & 63) << 1;
    *(float2*)&out[(size_t)v * H + j2] = *(const float2*)&h[(size_t)idx[v] * H + j2];
}

extern "C" void kernel_launch(void* const* d_in, const int* in_sizes, int n_in,
                              void* d_out, int out_size, void* d_ws, size_t ws_size,
                              hipStream_t stream) {
    const int*   ids    = (const int*)d_in[0];
    const int*   ast    = (const int*)d_in[1];
    const int*   mst    = (const int*)d_in[2];
    const int*   varpos = (const int*)d_in[3];
    const int*   predid = (const int*)d_in[4];
    const float* emb    = (const float*)d_in[5];
    const float* msg_W  = (const float*)d_in[6];
    const float* msg_b  = (const float*)d_in[7];
    const float* Wih_a  = (const float*)d_in[8];
    const float* Wih_b  = (const float*)d_in[9];
    const float* Whh    = (const float*)d_in[10];
    const float* bih    = (const float*)d_in[11];
    const float* bhh    = (const float*)d_in[12];

    float* out = (float*)d_out;
    float* h   = out;                              // h fp32 lives in d_out

    // d_out tail: CSR ints + fp16 weights + emb16 (dead before final out_gathers)
    int* ibase = (int*)(out + NH);
    int* deg4  = ibase;                            // 400000
    int* rp4   = ibase + 400000;                   // 400001
    int* cnt4  = ibase + 800001;                   // 400000
    int* col   = ibase + 1200001;                  // 240000
    int* part  = ibase + 1440001;                  // 256
    ushort_t* WT    = (ushort_t*)(ibase + 1500000);
    ushort_t* wmh   = WT;                          // 262144
    ushort_t* wml   = WT + 262144;
    ushort_t* B1h   = WT + 524288;                 // 327680
    ushort_t* B1l   = WT + 851968;
    ushort_t* B2h   = WT + 1179648;
    ushort_t* B2l   = WT + 1507328;
    ushort_t* emb16 = WT + 1835008;                // 1936384 (end 3771392 ush = 7.54MB <= 19.4MB tail)

    // workspace: exactly 153.6 MB
    if (ws_size < (size_t)153600000) return;
    char* wsb = (char*)d_ws;
    ushort_t* h16   = (ushort_t*)wsb;                      // 25.6 MB
    ushort_t* s1h   = (ushort_t*)(wsb + 25600000);         // 25.6 MB
    ushort_t* inc16 = (ushort_t*)(wsb + 51200000);         // 25.6 MB
    ushort_t* T2    = (ushort_t*)(wsb + 76800000);         // 51.2 MB: two quarters / rz (time-shared)
    ushort_t* rzhi  = T2;                                  // [NN][256] during gate phase
    ushort_t* zlo   = (ushort_t*)(wsb + 128000000);        // 25.6 MB

    embed_kernel<<<25000, 256, 0, stream>>>(ids, emb, h, h16);

    hipMemsetAsync(deg4, 0, N4 * sizeof(int), stream);
    hipMemsetAsync(cnt4, 0, N4 * sizeof(int), stream);
    count4_kernel<<<(E_TOT + 255) / 256, 256, 0, stream>>>(ast, mst, deg4);
    scan1b<<<196, 256, 0, stream>>>(deg4, rp4, part, N4);
    scan2<<<1, 256, 0, stream>>>(part, 196);
    scan3b<<<1563, 256, 0, stream>>>(rp4, part, N4, E_TOT);
    fill4_kernel<<<(E_TOT + 255) / 256, 256, 0, stream>>>(ast, mst, rp4, cnt4, col);
    prep_wmsg2<<<1024, 256, 0, stream>>>(msg_W, wmh, wml);
    prep_B2<<<1280, 256, 0, stream>>>(Wih_a, Wih_b, Whh, B1h, B1l, B2h, B2l);
    prep_emb16<<<7564, 256, 0, stream>>>(emb, emb16);

    const int LT[4] = {5, 2, 5, 2};
    const int Boff[4] = {0, 65536, 163840, 229376};
    for (int layer = 0; layer < 4; ++layer) {
        const float* bihL = bih + layer * 384;
        const float* bhhL = bhh + layer * 384;
        const float* mbL  = msg_b + (size_t)layer * 512;
        const ushort_t* B1hL = B1h + Boff[layer];
        const ushort_t* B1lL = B1l + Boff[layer];
        const ushort_t* B2hL = B2h + Boff[layer];
        const ushort_t* B2lL = B2l + Boff[layer];

        for (int ts = 0; ts < LT[layer]; ++ts) {
            // message transform + gather, two edge types at a time (T2 = 2 quarters)
            for (int half = 0; half < 2; ++half) {
                int e0 = half * 2;
                for (int ep = 0; ep < 2; ++ep) {
                    int e = e0 + ep;
                    msg_gemm<<<782, 256, 0, stream>>>(
                        h16, wmh + ((size_t)layer * 4 + e) * 16384,
                        wml + ((size_t)layer * 4 + e) * 16384, T2 + (size_t)ep * NH);
                }
                gather2<<<25000, 256, 0, stream>>>(T2, rp4, col, deg4, mbL, inc16, e0);
            }
            // gates (rz shares the T2 region — T2 is dead here, rewritten next timestep)
            if (layer == 0 || layer == 2) {
                gate_gemm<1,0><<<1563, 256, 0, stream>>>(inc16, h, h16, s1h, emb16, ids, B1hL, B1lL, rzhi, zlo, bihL, bhhL);
                gate_gemm<2,0><<<1563, 256, 0, stream>>>(inc16, h, h16, s1h, emb16, ids, B2hL, B2lL, rzhi, zlo, bihL, bhhL);
            } else if (layer == 1) {
                gate_gemm<1,1><<<1563, 256, 0, stream>>>(inc16, h, h16, s1h, emb16, ids, B1hL, B1lL, rzhi, zlo, bihL, bhhL);
                gate_gemm<2,1><<<1563, 256, 0, stream>>>(inc16, h, h16, s1h, emb16, ids, B2hL, B2lL, rzhi, zlo, bihL, bhhL);
            } else {
                gate_gemm<1,2><<<1563, 256, 0, stream>>>(inc16, h, h16, s1h, emb16, ids, B1hL, B1lL, rzhi, zlo, bihL, bhhL);
                gate_gemm<2,2><<<1563, 256, 0, stream>>>(inc16, h, h16, s1h, emb16, ids, B2hL, B2lL, rzhi, zlo, bihL, bhhL);
            }
        }
        if (layer == 0)
            hipMemcpyAsync(s1h, h16, (size_t)NH * 2, hipMemcpyDeviceToDevice, stream);
    }

    out_gather<<<(NV * 64 + 255) / 256, 256, 0, stream>>>(h, varpos, out + NH, NV);
    out_gather<<<(NP * 64 + 255) / 256, 256, 0, stream>>>(h, predid, out + NH + (size_t)NV * H, NP);
}

// Round 10
// 3558.055 us; speedup vs baseline: 2.3632x; 1.4174x over previous
//
#include <hip/hip_runtime.h>
#include <math.h>

#define H 128
#define NN 100000
#define E_AST 100000
#define E_MST 20000
#define E_TOT 240000
#define NV 30000
#define NP 8000
#define N4 400000
#define NH 12800000   // NN * H
#define VOCAB 15128

typedef unsigned short ushort_t;
typedef __attribute__((ext_vector_type(8))) unsigned short us8;
typedef _Float16 half8 __attribute__((ext_vector_type(8)));
typedef __attribute__((ext_vector_type(4))) float f32x4;

__device__ __forceinline__ unsigned short f2h(float f) {
    _Float16 h = (_Float16)f;
    return __builtin_bit_cast(unsigned short, h);
}
__device__ __forceinline__ float h2f(unsigned short u) {
    return (float)__builtin_bit_cast(_Float16, u);
}
__device__ __forceinline__ void fsplit(float x, unsigned short& hi, unsigned short& lo) {
    _Float16 a = (_Float16)x;
    _Float16 b = (_Float16)(x - (float)a);
    hi = __builtin_bit_cast(unsigned short, a);
    lo = __builtin_bit_cast(unsigned short, b);
}

#define GLD16(gsrc, ldst) __builtin_amdgcn_global_load_lds( \
    (const __attribute__((address_space(1))) unsigned int*)(gsrc), \
    (__attribute__((address_space(3))) unsigned int*)(ldst), 16, 0, 0)

// ---------------- embedding -> h pair (hi, lo) ----------------
__global__ void embed_kernel(const int* __restrict__ ids, const float* __restrict__ emb,
                             ushort_t* __restrict__ h16, ushort_t* __restrict__ hlo) {
    int g = blockIdx.x * 256 + threadIdx.x;
    if (g >= NN * 64) return;
    int i = g >> 6, j2 = (g & 63) << 1;
    float2 v = *(const float2*)&emb[(size_t)ids[i] * H + j2];
    unsigned short h0, l0, h1, l1;
    fsplit(v.x, h0, l0); fsplit(v.y, h1, l1);
    *(unsigned*)&h16[(size_t)i * H + j2] = (unsigned)h0 | ((unsigned)h1 << 16);
    *(unsigned*)&hlo[(size_t)i * H + j2] = (unsigned)l0 | ((unsigned)l1 << 16);
}

// ---------------- CSR build over keys (tgt*4 + e), payload src ----------------
__device__ inline void edge_decode(int t, const int* __restrict__ ast, const int* __restrict__ mst,
                                   int& e, int& src, int& tgt) {
    if (t < E_AST)                 { e = 0; src = ast[2*t];     tgt = ast[2*t+1]; }
    else if (t < 2*E_AST)          { int i = t - E_AST;         e = 1; src = ast[2*i+1]; tgt = ast[2*i]; }
    else if (t < 2*E_AST + E_MST)  { int i = t - 2*E_AST;       e = 2; src = mst[2*i];   tgt = mst[2*i+1]; }
    else                           { int i = t - 2*E_AST-E_MST; e = 3; src = mst[2*i+1]; tgt = mst[2*i]; }
}

__global__ void count4_kernel(const int* __restrict__ ast, const int* __restrict__ mst,
                              int* __restrict__ deg4) {
    int t = blockIdx.x * 256 + threadIdx.x;
    if (t >= E_TOT) return;
    int e, src, tgt; edge_decode(t, ast, mst, e, src, tgt);
    atomicAdd(&deg4[tgt * 4 + e], 1);
}

__global__ void scan1b(const int* __restrict__ deg, int* __restrict__ excl,
                       int* __restrict__ partial, int n) {
    __shared__ int sm[256];
    int t = threadIdx.x, b = blockIdx.x;
    int base = b * 2048 + t * 8;
    int v[8]; int s = 0;
    #pragma unroll
    for (int i = 0; i < 8; ++i) { v[i] = (base + i < n) ? deg[base + i] : 0; s += v[i]; }
    sm[t] = s;
    __syncthreads();
    for (int off = 1; off < 256; off <<= 1) {
        int x = (t >= off) ? sm[t - off] : 0;
        __syncthreads();
        sm[t] += x;
        __syncthreads();
    }
    int run = sm[t] - s;
    if (t == 255) partial[b] = sm[255];
    #pragma unroll
    for (int i = 0; i < 8; ++i) {
        if (base + i < n) { excl[base + i] = run; run += v[i]; }
    }
}

__global__ void scan2(int* __restrict__ partial, int nb) {
    __shared__ int sm[256];
    int t = threadIdx.x;
    int v = (t < nb) ? partial[t] : 0;
    sm[t] = v;
    __syncthreads();
    for (int off = 1; off < 256; off <<= 1) {
        int x = (t >= off) ? sm[t - off] : 0;
        __syncthreads();
        sm[t] += x;
        __syncthreads();
    }
    if (t < nb) partial[t] = sm[t] - v;
}

__global__ void scan3b(int* __restrict__ rp, const int* __restrict__ partial, int n, int etot) {
    int i = blockIdx.x * 256 + threadIdx.x;
    if (i < n) rp[i] += partial[i >> 11];
    if (i == n) rp[n] = etot;
}

__global__ void fill4_kernel(const int* __restrict__ ast, const int* __restrict__ mst,
                             const int* __restrict__ rp4, int* __restrict__ cnt4,
                             int* __restrict__ col) {
    int t = blockIdx.x * 256 + threadIdx.x;
    if (t >= E_TOT) return;
    int e, src, tgt; edge_decode(t, ast, mst, e, src, tgt);
    int key = tgt * 4 + e;
    int slot = rp4[key] + atomicAdd(&cnt4[key], 1);
    col[slot] = src;
}

// ---------------- weight prep ----------------
__global__ void prep_wmsg2(const float* __restrict__ W, ushort_t* __restrict__ hi,
                           ushort_t* __restrict__ lo) {
    int i = blockIdx.x * 256 + threadIdx.x;
    if (i >= 262144) return;
    fsplit(W[i], hi[i], lo[i]);
}

__global__ void prep_emb16(const float* __restrict__ emb, ushort_t* __restrict__ emb16) {
    int i = blockIdx.x * 256 + threadIdx.x;
    if (i >= VOCAB * H) return;
    emb16[i] = f2h(emb[i]);
}

// B1 rows 2j/2j+1 = r_j/z_j over K=[Wih | Whh]; B2 rows 2j/2j+1 = inn_j(Wih,0) / hn_j(0,Whh)
__global__ void prep_B2(const float* __restrict__ Wih_a, const float* __restrict__ Wih_b,
                        const float* __restrict__ Whh,
                        ushort_t* __restrict__ B1h, ushort_t* __restrict__ B1l,
                        ushort_t* __restrict__ B2h, ushort_t* __restrict__ B2l) {
    int i = blockIdx.x * 256 + threadIdx.x;
    if (i >= 327680) return;
    int l, off, K;
    if (i < 65536)       { l = 0; off = 0;      K = 256; }
    else if (i < 163840) { l = 1; off = 65536;  K = 384; }
    else if (i < 229376) { l = 2; off = 163840; K = 256; }
    else                 { l = 3; off = 229376; K = 384; }
    int Kx = K - 128;
    const float* Wih = (l & 1) ? (Wih_b + (size_t)(l >> 1) * 384 * 256)
                               : (Wih_a + (size_t)(l >> 1) * 384 * 128);
    const float* WhhL = Whh + (size_t)l * 384 * 128;
    int rem = i - off;
    int row = rem / K, k = rem - row * K;
    int j = row >> 1, s = row & 1;
    int g1 = s * 128 + j;
    float v1 = (k < Kx) ? Wih[(size_t)g1 * Kx + k] : WhhL[(size_t)g1 * 128 + (k - Kx)];
    fsplit(v1, B1h[i], B1l[i]);
    int g2 = 256 + j;
    float v2;
    if (s == 0) v2 = (k < Kx) ? Wih[(size_t)g2 * Kx + k] : 0.f;
    else        v2 = (k < Kx) ? 0.f : WhhL[(size_t)g2 * 128 + (k - Kx)];
    fsplit(v2, B2h[i], B2l[i]);
}

// ---------------- msg GEMM (merged N=512): T_all = h16 @ Wmsg^T, transposed epilogue ----------------
// grid (782, 4); by selects 128-col slab; dest: by<2 -> TA, else TB (each [NN][256])
__global__ __launch_bounds__(256, 4) void msg_gemm(
    const ushort_t* __restrict__ h16, const ushort_t* __restrict__ Whi,
    const ushort_t* __restrict__ Wlo, ushort_t* __restrict__ TA, ushort_t* __restrict__ TB)
{
    __shared__ ushort_t sh[16384];            // Ah[0:8192], Bs[8192:16384]
    ushort_t* Ah = sh;
    ushort_t* Bs = sh + 8192;
    const int tid = threadIdx.x, w = tid >> 6, l = tid & 63;
    const int m0 = blockIdx.x * 128;
    const int n0 = blockIdx.y * 128;
    const int wm = w >> 1, wn = w & 1;
    const int lr8 = l >> 3, lslot = (l & 7) ^ lr8;
    f32x4 acc[4][4];
    #pragma unroll
    for (int a = 0; a < 4; ++a)
        #pragma unroll
        for (int b = 0; b < 4; ++b) acc[a][b] = (f32x4){0.f, 0.f, 0.f, 0.f};

    for (int kt = 0; kt < 2; ++kt) {
        const int kk = kt * 64;
        #pragma unroll
        for (int q = 0; q < 4; ++q) {
            int row8 = w * 4 + q;
            int grow = m0 + row8 * 8 + lr8; if (grow >= NN) grow = NN - 1;
            GLD16(h16 + (size_t)grow * H + kk + lslot * 8, Ah + row8 * 512);
        }
        #pragma unroll
        for (int q = 0; q < 4; ++q) {
            int row8 = w * 4 + q;
            GLD16(Whi + (size_t)(n0 + row8 * 8 + lr8) * 128 + kk + lslot * 8, Bs + row8 * 512);
        }
        __syncthreads();
        #pragma unroll
        for (int fk = 0; fk < 2; ++fk) {
            half8 av[4], bv[4];
            #pragma unroll
            for (int fm = 0; fm < 4; ++fm) {
                int row = wm * 64 + fm * 16 + (l & 15);
                int slot = (fk * 4 + (l >> 4)) ^ (row & 7);
                av[fm] = *(const half8*)&Ah[row * 64 + slot * 8];
            }
            #pragma unroll
            for (int fn = 0; fn < 4; ++fn) {
                int row = wn * 64 + fn * 16 + (l & 15);
                int slot = (fk * 4 + (l >> 4)) ^ (row & 7);
                bv[fn] = *(const half8*)&Bs[row * 64 + slot * 8];
            }
            #pragma unroll
            for (int fm = 0; fm < 4; ++fm)
                #pragma unroll
                for (int fn = 0; fn < 4; ++fn)
                    acc[fm][fn] = __builtin_amdgcn_mfma_f32_16x16x32_f16(av[fm], bv[fn], acc[fm][fn], 0, 0, 0);
        }
        __syncthreads();
        #pragma unroll
        for (int q = 0; q < 4; ++q) {
            int row8 = w * 4 + q;
            GLD16(Wlo + (size_t)(n0 + row8 * 8 + lr8) * 128 + kk + lslot * 8, Bs + row8 * 512);
        }
        __syncthreads();
        #pragma unroll
        for (int fk = 0; fk < 2; ++fk) {
            half8 av[4], bv[4];
            #pragma unroll
            for (int fm = 0; fm < 4; ++fm) {
                int row = wm * 64 + fm * 16 + (l & 15);
                int slot = (fk * 4 + (l >> 4)) ^ (row & 7);
                av[fm] = *(const half8*)&Ah[row * 64 + slot * 8];
            }
            #pragma unroll
            for (int fn = 0; fn < 4; ++fn) {
                int row = wn * 64 + fn * 16 + (l & 15);
                int slot = (fk * 4 + (l >> 4)) ^ (row & 7);
                bv[fn] = *(const half8*)&Bs[row * 64 + slot * 8];
            }
            #pragma unroll
            for (int fm = 0; fm < 4; ++fm)
                #pragma unroll
                for (int fn = 0; fn < 4; ++fn)
                    acc[fm][fn] = __builtin_amdgcn_mfma_f32_16x16x32_f16(av[fm], bv[fn], acc[fm][fn], 0, 0, 0);
        }
        __syncthreads();
    }
    // transposed epilogue: acc -> LDS tile [128][128] fp16 -> coalesced stores
    #pragma unroll
    for (int fm = 0; fm < 4; ++fm)
        #pragma unroll
        for (int fn = 0; fn < 4; ++fn) {
            int colL = wn * 64 + fn * 16 + (l & 15);
            #pragma unroll
            for (int rg = 0; rg < 4; ++rg) {
                int rowL = wm * 64 + fm * 16 + (l >> 4) * 4 + rg;
                sh[rowL * 128 + colL] = f2h(acc[fm][fn][rg]);
            }
        }
    __syncthreads();
    {
        int row = tid >> 1, half = tid & 1;
        int grow = m0 + row;
        if (grow < NN) {
            ushort_t* dst = ((blockIdx.y < 2) ? TA : TB) + (size_t)grow * 256 + (blockIdx.y & 1) * 128 + half * 64;
            const ushort_t* src = &sh[row * 128 + half * 64];
            #pragma unroll
            for (int q = 0; q < 8; ++q)
                *(us8*)&dst[q * 8] = *(const us8*)&src[q * 8];
        }
    }
}

// ---------------- gather all 4 edge types: inc16 = deg-bias + sum T_all[src] ----------------
__global__ void gather_all(const ushort_t* __restrict__ TA, const ushort_t* __restrict__ TB,
                           const int* __restrict__ rp4, const int* __restrict__ col,
                           const int* __restrict__ deg4, const float* __restrict__ mb,
                           ushort_t* __restrict__ inc16) {
    int wv = threadIdx.x >> 6, l = threadIdx.x & 63;
    int t = blockIdx.x * 4 + wv;
    if (t >= NN) return;
    int c2 = l * 2;
    float a0 = 0.f, a1 = 0.f;
    #pragma unroll
    for (int e4 = 0; e4 < 4; ++e4) {
        float d = (float)deg4[t * 4 + e4];
        a0 += d * mb[e4 * H + c2];
        a1 += d * mb[e4 * H + c2 + 1];
    }
    #pragma unroll
    for (int e = 0; e < 4; ++e) {
        const ushort_t* Tb = (e < 2) ? TA : TB;
        int cb = (e & 1) * 128;
        int s0 = rp4[4 * t + e], s1 = rp4[4 * t + e + 1];
        for (int s = s0; s < s1; ++s) {
            unsigned vv = *(const unsigned*)&Tb[(size_t)col[s] * 256 + cb + c2];
            a0 += h2f((unsigned short)(vv & 0xffff));
            a1 += h2f((unsigned short)(vv >> 16));
        }
    }
    *(unsigned*)&inc16[(size_t)t * H + c2] = (unsigned)f2h(a0) | ((unsigned)f2h(a1) << 16);
}

// ---------------- fused GRU: pass1 (r,z in fp32 regs) + pass2 (inn,hn + epilogue) ----------------
// M-tile 32, grid 3125 (exact). CFG 0: [inc,h] K=256; 1: [inc,emb16,h]; 2: [inc,s1h,h]
template<int CFG>
__global__ __launch_bounds__(256, 3) void gru_fused(
    const ushort_t* __restrict__ inc16, ushort_t* __restrict__ h16, ushort_t* __restrict__ hlo,
    const ushort_t* __restrict__ s1h, const ushort_t* __restrict__ emb16, const int* __restrict__ ids,
    const ushort_t* __restrict__ B1h, const ushort_t* __restrict__ B1l,
    const ushort_t* __restrict__ B2h, const ushort_t* __restrict__ B2l,
    const float* __restrict__ bihL, const float* __restrict__ bhhL)
{
    constexpr int NPARTS = (CFG == 0) ? 2 : 3;
    constexpr int K = NPARTS * 128;
    __shared__ ushort_t sh[18432];            // 36KB: Ah[0:2048], Bs[2048:18432]
    ushort_t* Ah = sh;
    ushort_t* Bs = sh + 2048;
    const int tid = threadIdx.x, w = tid >> 6, l = tid & 63;
    const int m0 = blockIdx.x * 32;           // 3125*32 == 100000
    const int lr8 = l >> 3, lslot = (l & 7) ^ lr8;

    float rzr[2][4][4], rzz[2][4][4];
    f32x4 acc[2][4];

    #pragma unroll
    for (int pass = 0; pass < 2; ++pass) {
        const ushort_t* Bh = pass ? B2h : B1h;
        const ushort_t* Bl = pass ? B2l : B1l;
        #pragma unroll
        for (int a = 0; a < 2; ++a)
            #pragma unroll
            for (int b = 0; b < 4; ++b) acc[a][b] = (f32x4){0.f, 0.f, 0.f, 0.f};

        for (int kt = 0; kt < NPARTS * 2; ++kt) {
            const int p = kt >> 1;
            const int kk = (kt & 1) * 64;
            const int kb = p * 128 + kk;
            // A: one GLD16 per thread (rows w*8 .. w*8+7 per wave)
            {
                int grow = m0 + w * 8 + lr8;
                const ushort_t* sb;
                if (p == 0)               sb = inc16 + (size_t)grow * H;
                else if (p == NPARTS - 1) sb = h16 + (size_t)grow * H;
                else if (CFG == 1)        sb = emb16 + (size_t)ids[grow] * H;
                else                      sb = s1h + (size_t)grow * H;
                GLD16(sb + kk + lslot * 8, Ah + w * 512);
            }
            #pragma unroll
            for (int q = 0; q < 8; ++q)
                GLD16(Bh + (size_t)((w * 8 + q) * 8 + lr8) * K + kb + lslot * 8, Bs + (w * 8 + q) * 512);
            __syncthreads();
            #pragma unroll
            for (int fk = 0; fk < 2; ++fk) {
                half8 av[2], bv[4];
                #pragma unroll
                for (int fm = 0; fm < 2; ++fm) {
                    int row = fm * 16 + (l & 15);
                    int slot = (fk * 4 + (l >> 4)) ^ (row & 7);
                    av[fm] = *(const half8*)&Ah[row * 64 + slot * 8];
                }
                #pragma unroll
                for (int fn = 0; fn < 4; ++fn) {
                    int row = w * 64 + fn * 16 + (l & 15);
                    int slot = (fk * 4 + (l >> 4)) ^ (row & 7);
                    bv[fn] = *(const half8*)&Bs[row * 64 + slot * 8];
                }
                #pragma unroll
                for (int fm = 0; fm < 2; ++fm)
                    #pragma unroll
                    for (int fn = 0; fn < 4; ++fn)
                        acc[fm][fn] = __builtin_amdgcn_mfma_f32_16x16x32_f16(av[fm], bv[fn], acc[fm][fn], 0, 0, 0);
            }
            __syncthreads();
            #pragma unroll
            for (int q = 0; q < 8; ++q)
                GLD16(Bl + (size_t)((w * 8 + q) * 8 + lr8) * K + kb + lslot * 8, Bs + (w * 8 + q) * 512);
            __syncthreads();
            #pragma unroll
            for (int fk = 0; fk < 2; ++fk) {
                half8 av[2], bv[4];
                #pragma unroll
                for (int fm = 0; fm < 2; ++fm) {
                    int row = fm * 16 + (l & 15);
                    int slot = (fk * 4 + (l >> 4)) ^ (row & 7);
                    av[fm] = *(const half8*)&Ah[row * 64 + slot * 8];
                }
                #pragma unroll
                for (int fn = 0; fn < 4; ++fn) {
                    int row = w * 64 + fn * 16 + (l & 15);
                    int slot = (fk * 4 + (l >> 4)) ^ (row & 7);
                    bv[fn] = *(const half8*)&Bs[row * 64 + slot * 8];
                }
                #pragma unroll
                for (int fm = 0; fm < 2; ++fm)
                    #pragma unroll
                    for (int fn = 0; fn < 4; ++fn)
                        acc[fm][fn] = __builtin_amdgcn_mfma_f32_16x16x32_f16(av[fm], bv[fn], acc[fm][fn], 0, 0, 0);
            }
            __syncthreads();
        }

        if (pass == 0) {
            // sigmoid + stash r,z in fp32 regs (both lanes of each pair hold both values)
            #pragma unroll
            for (int fn = 0; fn < 4; ++fn) {
                int cc = w * 64 + fn * 16 + (l & 15);
                int j = cc >> 1, s = cc & 1;
                float bsum = s ? (bihL[128 + j] + bhhL[128 + j]) : (bihL[j] + bhhL[j]);
                #pragma unroll
                for (int fm = 0; fm < 2; ++fm)
                    #pragma unroll
                    for (int rg = 0; rg < 4; ++rg) {
                        float g = 1.f / (1.f + __expf(-(acc[fm][fn][rg] + bsum)));
                        float other = __shfl_xor(g, 1);
                        rzr[fm][fn][rg] = s ? other : g;
                        rzz[fm][fn][rg] = s ? g : other;
                    }
            }
        } else {
            // GRU epilogue: compute o, split to hi/lo, stage in LDS, coalesced writeout
            ushort_t* ohi = Bs;
            ushort_t* olo = Bs + 4096;
            #pragma unroll
            for (int fn = 0; fn < 4; ++fn) {
                int cc = w * 64 + fn * 16 + (l & 15);
                int j = cc >> 1, s = cc & 1;
                float bsum = s ? bhhL[256 + j] : bihL[256 + j];
                #pragma unroll
                for (int fm = 0; fm < 2; ++fm)
                    #pragma unroll
                    for (int rg = 0; rg < 4; ++rg) {
                        float self = acc[fm][fn][rg] + bsum;
                        float other = __shfl_xor(self, 1);
                        if (s == 0) {
                            int rl = fm * 16 + (l >> 4) * 4 + rg;
                            int row = m0 + rl;
                            float n = tanhf(self + rzr[fm][fn][rg] * other);
                            float hold = h2f(h16[(size_t)row * H + j]) + h2f(hlo[(size_t)row * H + j]);
                            float z = rzz[fm][fn][rg];
                            float o = (1.f - z) * n + z * hold;
                            unsigned short hi, lo;
                            fsplit(o, hi, lo);
                            ohi[rl * 128 + j] = hi;
                            olo[rl * 128 + j] = lo;
                        }
                    }
            }
            __syncthreads();
            {
                int row = tid >> 3, seg = tid & 7;
                size_t go = (size_t)(m0 + row) * H + seg * 16;
                *(us8*)&h16[go]     = *(const us8*)&ohi[row * 128 + seg * 16];
                *(us8*)&h16[go + 8] = *(const us8*)&ohi[row * 128 + seg * 16 + 8];
                *(us8*)&hlo[go]     = *(const us8*)&olo[row * 128 + seg * 16];
                *(us8*)&hlo[go + 8] = *(const us8*)&olo[row * 128 + seg * 16 + 8];
            }
        }
    }
}

// ---------------- final reconstruct h fp32 -> d_out, then gathers ----------------
__global__ void recon_kernel(const ushort_t* __restrict__ h16, const ushort_t* __restrict__ hlo,
                             float* __restrict__ out) {
    int g = blockIdx.x * 256 + threadIdx.x;
    if (g >= NN * 64) return;
    unsigned hi2 = *(const unsigned*)&h16[(size_t)g * 2];
    unsigned lo2 = *(const unsigned*)&hlo[(size_t)g * 2];
    float2 o;
    o.x = h2f((unsigned short)(hi2 & 0xffff)) + h2f((unsigned short)(lo2 & 0xffff));
    o.y = h2f((unsigned short)(hi2 >> 16)) + h2f((unsigned short)(lo2 >> 16));
    *(float2*)&out[(size_t)g * 2] = o;
}

__global__ void out_gather(const float* __restrict__ h, const int* __restrict__ idx,
                           float* __restrict__ out, int n) {
    int g = blockIdx.x * 256 + threadIdx.x;
    if (g >= n * 64) return;
    int v = g >> 6, j2 = (g & 63) << 1;
    *(float2*)&out[(size_t)v * H + j2] = *(const float2*)&h[(size_t)idx[v] * H + j2];
}

extern "C" void kernel_launch(void* const* d_in, const int* in_sizes, int n_in,
                              void* d_out, int out_size, void* d_ws, size_t ws_size,
                              hipStream_t stream) {
    const int*   ids    = (const int*)d_in[0];
    const int*   ast    = (const int*)d_in[1];
    const int*   mst    = (const int*)d_in[2];
    const int*   varpos = (const int*)d_in[3];
    const int*   predid = (const int*)d_in[4];
    const float* emb    = (const float*)d_in[5];
    const float* msg_W  = (const float*)d_in[6];
    const float* msg_b  = (const float*)d_in[7];
    const float* Wih_a  = (const float*)d_in[8];
    const float* Wih_b  = (const float*)d_in[9];
    const float* Whh    = (const float*)d_in[10];
    const float* bih    = (const float*)d_in[11];
    const float* bhh    = (const float*)d_in[12];

    float* out = (float*)d_out;
    ushort_t* TB = (ushort_t*)out;                 // [NN][256] fp16 = 51.2MB, reused until recon

    // d_out tail: CSR ints + fp16 weights + emb16 (overwritten by final gathers)
    int* ibase = (int*)(out + NH);
    int* deg4  = ibase;                            // 400000
    int* rp4   = ibase + 400000;                   // 400001
    int* cnt4  = ibase + 800001;                   // 400000
    int* col   = ibase + 1200001;                  // 240000
    int* part  = ibase + 1440001;                  // 256
    ushort_t* WT    = (ushort_t*)(ibase + 1500000);
    ushort_t* wmh   = WT;                          // 262144
    ushort_t* wml   = WT + 262144;
    ushort_t* B1h   = WT + 524288;                 // 327680
    ushort_t* B1l   = WT + 851968;
    ushort_t* B2h   = WT + 1179648;
    ushort_t* B2l   = WT + 1507328;
    ushort_t* emb16 = WT + 1835008;                // 1936384 -> end ~7.5MB of 19.4MB tail

    if (ws_size < (size_t)153600000) return;
    char* wsb = (char*)d_ws;
    ushort_t* h16   = (ushort_t*)wsb;                      // 25.6 MB
    ushort_t* hlo   = (ushort_t*)(wsb + 25600000);         // 25.6 MB
    ushort_t* s1h   = (ushort_t*)(wsb + 51200000);         // 25.6 MB
    ushort_t* inc16 = (ushort_t*)(wsb + 76800000);         // 25.6 MB
    ushort_t* TA    = (ushort_t*)(wsb + 102400000);        // 51.2 MB: [NN][256] fp16

    embed_kernel<<<25000, 256, 0, stream>>>(ids, emb, h16, hlo);

    hipMemsetAsync(deg4, 0, N4 * sizeof(int), stream);
    hipMemsetAsync(cnt4, 0, N4 * sizeof(int), stream);
    count4_kernel<<<(E_TOT + 255) / 256, 256, 0, stream>>>(ast, mst, deg4);
    scan1b<<<196, 256, 0, stream>>>(deg4, rp4, part, N4);
    scan2<<<1, 256, 0, stream>>>(part, 196);
    scan3b<<<1563, 256, 0, stream>>>(rp4, part, N4, E_TOT);
    fill4_kernel<<<(E_TOT + 255) / 256, 256, 0, stream>>>(ast, mst, rp4, cnt4, col);
    prep_wmsg2<<<1024, 256, 0, stream>>>(msg_W, wmh, wml);
    prep_B2<<<1280, 256, 0, stream>>>(Wih_a, Wih_b, Whh, B1h, B1l, B2h, B2l);
    prep_emb16<<<7564, 256, 0, stream>>>(emb, emb16);

    const int LT[4] = {5, 2, 5, 2};
    const int Boff[4] = {0, 65536, 163840, 229376};
    for (int layer = 0; layer < 4; ++layer) {
        const float* bihL = bih + layer * 384;
        const float* bhhL = bhh + layer * 384;
        const float* mbL  = msg_b + (size_t)layer * 512;
        const ushort_t* wmhL = wmh + (size_t)layer * 65536;
        const ushort_t* wmlL = wml + (size_t)layer * 65536;
        const ushort_t* B1hL = B1h + Boff[layer];
        const ushort_t* B1lL = B1l + Boff[layer];
        const ushort_t* B2hL = B2h + Boff[layer];
        const ushort_t* B2lL = B2l + Boff[layer];

        for (int ts = 0; ts < LT[layer]; ++ts) {
            msg_gemm<<<dim3(782, 4), 256, 0, stream>>>(h16, wmhL, wmlL, TA, TB);
            gather_all<<<25000, 256, 0, stream>>>(TA, TB, rp4, col, deg4, mbL, inc16);
            if (layer == 0 || layer == 2)
                gru_fused<0><<<3125, 256, 0, stream>>>(inc16, h16, hlo, s1h, emb16, ids,
                    B1hL, B1lL, B2hL, B2lL, bihL, bhhL);
            else if (layer == 1)
                gru_fused<1><<<3125, 256, 0, stream>>>(inc16, h16, hlo, s1h, emb16, ids,
                    B1hL, B1lL, B2hL, B2lL, bihL, bhhL);
            else
                gru_fused<2><<<3125, 256, 0, stream>>>(inc16, h16, hlo, s1h, emb16, ids,
                    B1hL, B1lL, B2hL, B2lL, bihL, bhhL);
        }
        if (layer == 0)
            hipMemcpyAsync(s1h, h16, (size_t)NH * 2, hipMemcpyDeviceToDevice, stream);
    }

    recon_kernel<<<25000, 256, 0, stream>>>(h16, hlo, out);
    out_gather<<<(NV * 64 + 255) / 256, 256, 0, stream>>>(out, varpos, out + NH, NV);
    out_gather<<<(NP * 64 + 255) / 256, 256, 0, stream>>>(out, predid, out + NH + (size_t)NV * H, NP);
}